// Round 9
// baseline (3449.151 us; speedup 1.0000x reference)
//
// MANN/NTM forward — R18: NBAT=2 -> 4 (64 blocks). Weight-stream cost per step
// (~1MB/block, latency-bound, geometry-pinned by R11-R16) is independent of
// batch count — serve 4 batches per stream instead of 2. GEMV lane geometry,
// PIPE4, rotations all IDENTICAL to R9/R17; only the batch-vector width at
// each weight float4 changes (h2/c2/r2 now [k*4+i], one float4 LDS read).
// LDS hand-summed 159,780B < 163,840. Local phases (P3,P5-P12) double per
// block; GEMV stream cost ~unchanged -> per-step +25-40%, throughput 2x.
// gemm_in2 (split-bf16 MFMA, R17) and prep unchanged.
#include <hip/hip_runtime.h>
#include <math.h>

#define TB   100
#define BB   256
#define INF_ 784
#define HH   200
#define RR   4
#define NN   128
#define DD   40
#define NCLS 5
#define G4H  800   // 4*H
#define KAW  324   // 160 key + 160 add + 1 sigma + 3 pad
#define MST  44    // padded M row stride
#define NBAT 4     // batches per block
#define NBLK (BB / NBAT)

typedef __attribute__((ext_vector_type(8))) short bf16x8;
typedef __attribute__((ext_vector_type(4))) float f32x4;

__device__ __forceinline__ float sigmoidf_(float x) { return 1.0f / (1.0f + expf(-x)); }

__device__ __forceinline__ void splitbf_(float v, unsigned short &hi, unsigned short &lo) {
  const unsigned b = __float_as_uint(v);
  hi = (unsigned short)(b >> 16);
  const float hf = __uint_as_float(b & 0xFFFF0000u);
  lo = (unsigned short)(__float_as_uint(v - hf) >> 16);
}

#define ADV(c, CC) { ++(c); if ((c) == (CC)) (c) = 0; }

// 4-slot rotating software pipeline (3 chunks of loads in flight ahead of FMA).
#define PIPE4(CC, OFS, LOADM, FMAM)                                     \
  {                                                                     \
    int chL = (OFS), chF = (OFS);                                       \
    LOADM(w0, chL); ADV(chL, CC); LOADM(w1, chL); ADV(chL, CC);         \
    LOADM(w2, chL); ADV(chL, CC);                                       \
    _Pragma("unroll 1")                                                 \
    for (int g = 0; g < ((CC) - 3) / 4; ++g) {                          \
      LOADM(w3, chL); ADV(chL, CC); FMAM(w0, chF); ADV(chF, CC);        \
      LOADM(w0, chL); ADV(chL, CC); FMAM(w1, chF); ADV(chF, CC);        \
      LOADM(w1, chL); ADV(chL, CC); FMAM(w2, chF); ADV(chF, CC);        \
      LOADM(w2, chL); ADV(chL, CC); FMAM(w3, chF); ADV(chF, CC);        \
    }                                                                   \
    {                                                                   \
      constexpr int REMX = (CC) - 3 - 4 * (((CC) - 3) / 4);             \
      if (REMX >= 1) { LOADM(w3, chL); ADV(chL, CC); }                  \
      FMAM(w0, chF); ADV(chF, CC);                                      \
      if (REMX >= 2) { LOADM(w0, chL); ADV(chL, CC); }                  \
      FMAM(w1, chF); ADV(chF, CC);                                      \
      if (REMX >= 3) { LOADM(w1, chL); ADV(chL, CC); }                  \
      FMAM(w2, chF); ADV(chF, CC);                                      \
      if (REMX >= 1) { FMAM(w3, chF); ADV(chF, CC); }                   \
      if (REMX >= 2) { FMAM(w0, chF); ADV(chF, CC); }                   \
      if (REMX >= 3) { FMAM(w1, chF); ADV(chF, CC); }                   \
    }                                                                   \
  }

// ---------------------------------------------------------------------------
// Prep: transpose weights into GEMV-friendly (k-major) layouts in workspace.
// ---------------------------------------------------------------------------
__global__ __launch_bounds__(256) void prep_kernel(
    const float* __restrict__ Whh, const float* __restrict__ Wrh,
    const float* __restrict__ Wkey, const float* __restrict__ Wadd,
    const float* __restrict__ Wsig, const float* __restrict__ bkey,
    const float* __restrict__ badd, const float* __restrict__ bsig,
    float* __restrict__ WhhT, float* __restrict__ WrhT,
    float* __restrict__ WkaT, float* __restrict__ bka)
{
  const int tid = blockIdx.x * 256 + threadIdx.x;
  if (tid < 160000) {            // Whh (800,200) -> WhhT (200,800)
    const int j = tid / 200, k = tid - j * 200;
    WhhT[k * G4H + j] = Whh[tid];
  }
  if (tid < 32000) {             // Wrh (200,160) -> WrhT (160,200)
    const int k = tid / 160, m = tid - k * 160;
    WrhT[m * HH + k] = Wrh[tid];
  }
  if (tid < 200 * KAW) {         // [Wkey(160,200)|Wadd(160,200)|Wsig(1,200)]^T
    const int k = tid / KAW, j = tid - k * KAW;
    float v = 0.0f;
    if (j < 160)       v = Wkey[j * HH + k];
    else if (j < 320)  v = Wadd[(j - 160) * HH + k];
    else if (j == 320) v = Wsig[k];
    WkaT[tid] = v;
  }
  if (tid < KAW) {
    float v = 0.0f;
    if (tid < 160)       v = bkey[tid];
    else if (tid < 320)  v = badd[tid - 160];
    else if (tid == 320) v = bsig[0];
    bka[tid] = v;
  }
}

// ---------------------------------------------------------------------------
// gemm_in2: G[m,j] = sum_k x[m,k]*Wih[j,k] + bih[j] + bhh[j]  (MFMA bf16,
// split-precision hi/lo). Tile 128(M) x 80(N), 256 thr = 4 waves, K-step 32.
// ---------------------------------------------------------------------------
#define GM  128
#define GN  80
#define LDK 40   // padded K stride in bf16 elems (80B, 16B-aligned rows)

__global__ __launch_bounds__(256) void gemm_in2_kernel(
    const float* __restrict__ X, const float* __restrict__ Wih,
    const float* __restrict__ bih, const float* __restrict__ bhh,
    float* __restrict__ G)
{
  __shared__ __attribute__((aligned(16))) unsigned short Ahi[GM][LDK];
  __shared__ __attribute__((aligned(16))) unsigned short Alo[GM][LDK];
  __shared__ __attribute__((aligned(16))) unsigned short Bhi[GN][LDK];
  __shared__ __attribute__((aligned(16))) unsigned short Blo[GN][LDK];

  const int tid  = threadIdx.x;
  const int wv   = tid >> 6, lane = tid & 63;
  const int n0   = blockIdx.x * GN;
  const int m0   = blockIdx.y * GM;

  f32x4 acc[2][5];
#pragma unroll
  for (int mt = 0; mt < 2; ++mt)
#pragma unroll
    for (int nt = 0; nt < 5; ++nt) acc[mt][nt] = (f32x4){0.f, 0.f, 0.f, 0.f};

  const int arow = tid >> 1, ak = (tid & 1) * 16;
  const float* Ap = X + (size_t)(m0 + arow) * INF_ + ak;
  const float* Bp = Wih + (size_t)(n0 + arow) * INF_ + ak;  // arow<80 when tid<160

  const int fr = lane & 15, fk = (lane >> 4) * 8;

  for (int kk = 0; kk < 800; kk += 32) {
    // ---- global loads (zero-padded past K=784; 784%16==0 so per-16 guard) ----
    float va[16], vb[16];
    const bool av = (kk + ak) < INF_;
#pragma unroll
    for (int i = 0; i < 16; ++i) va[i] = 0.f;
    if (av) {
      *(float4*)&va[0]  = *(const float4*)(Ap + kk);
      *(float4*)&va[4]  = *(const float4*)(Ap + kk + 4);
      *(float4*)&va[8]  = *(const float4*)(Ap + kk + 8);
      *(float4*)&va[12] = *(const float4*)(Ap + kk + 12);
    }
    if (tid < 160) {
#pragma unroll
      for (int i = 0; i < 16; ++i) vb[i] = 0.f;
      if (av) {
        *(float4*)&vb[0]  = *(const float4*)(Bp + kk);
        *(float4*)&vb[4]  = *(const float4*)(Bp + kk + 4);
        *(float4*)&vb[8]  = *(const float4*)(Bp + kk + 8);
        *(float4*)&vb[12] = *(const float4*)(Bp + kk + 12);
      }
    }
    __syncthreads();   // prior compute done before LDS overwrite
    // ---- convert + store to LDS ----
    {
      unsigned ah[8], al[8];
#pragma unroll
      for (int i = 0; i < 8; ++i) {
        unsigned short h0, l0, h1, l1;
        splitbf_(va[2 * i], h0, l0);
        splitbf_(va[2 * i + 1], h1, l1);
        ah[i] = (unsigned)h0 | ((unsigned)h1 << 16);
        al[i] = (unsigned)l0 | ((unsigned)l1 << 16);
      }
      ((int4*)&Ahi[arow][ak])[0] = make_int4(ah[0], ah[1], ah[2], ah[3]);
      ((int4*)&Ahi[arow][ak + 8])[0] = make_int4(ah[4], ah[5], ah[6], ah[7]);
      ((int4*)&Alo[arow][ak])[0] = make_int4(al[0], al[1], al[2], al[3]);
      ((int4*)&Alo[arow][ak + 8])[0] = make_int4(al[4], al[5], al[6], al[7]);
    }
    if (tid < 160) {
      unsigned bh[8], bl[8];
#pragma unroll
      for (int i = 0; i < 8; ++i) {
        unsigned short h0, l0, h1, l1;
        splitbf_(vb[2 * i], h0, l0);
        splitbf_(vb[2 * i + 1], h1, l1);
        bh[i] = (unsigned)h0 | ((unsigned)h1 << 16);
        bl[i] = (unsigned)l0 | ((unsigned)l1 << 16);
      }
      ((int4*)&Bhi[arow][ak])[0] = make_int4(bh[0], bh[1], bh[2], bh[3]);
      ((int4*)&Bhi[arow][ak + 8])[0] = make_int4(bh[4], bh[5], bh[6], bh[7]);
      ((int4*)&Blo[arow][ak])[0] = make_int4(bl[0], bl[1], bl[2], bl[3]);
      ((int4*)&Blo[arow][ak + 8])[0] = make_int4(bl[4], bl[5], bl[6], bl[7]);
    }
    __syncthreads();
    // ---- MFMA: 2 m-tiles x 5 n-tiles x 3 passes ----
    const bf16x8 a0h = *(const bf16x8*)&Ahi[wv * 32 + fr][fk];
    const bf16x8 a0l = *(const bf16x8*)&Alo[wv * 32 + fr][fk];
    const bf16x8 a1h = *(const bf16x8*)&Ahi[wv * 32 + 16 + fr][fk];
    const bf16x8 a1l = *(const bf16x8*)&Alo[wv * 32 + 16 + fr][fk];
#pragma unroll
    for (int nt = 0; nt < 5; ++nt) {
      const bf16x8 bh = *(const bf16x8*)&Bhi[nt * 16 + fr][fk];
      const bf16x8 bl = *(const bf16x8*)&Blo[nt * 16 + fr][fk];
      acc[0][nt] = __builtin_amdgcn_mfma_f32_16x16x32_bf16(a0h, bh, acc[0][nt], 0, 0, 0);
      acc[1][nt] = __builtin_amdgcn_mfma_f32_16x16x32_bf16(a1h, bh, acc[1][nt], 0, 0, 0);
      acc[0][nt] = __builtin_amdgcn_mfma_f32_16x16x32_bf16(a0l, bh, acc[0][nt], 0, 0, 0);
      acc[1][nt] = __builtin_amdgcn_mfma_f32_16x16x32_bf16(a1l, bh, acc[1][nt], 0, 0, 0);
      acc[0][nt] = __builtin_amdgcn_mfma_f32_16x16x32_bf16(a0h, bl, acc[0][nt], 0, 0, 0);
      acc[1][nt] = __builtin_amdgcn_mfma_f32_16x16x32_bf16(a1h, bl, acc[1][nt], 0, 0, 0);
    }
  }

  // ---- epilogue: D col = lane&15, row = (lane>>4)*4 + reg ----
#pragma unroll
  for (int nt = 0; nt < 5; ++nt) {
    const int en = n0 + nt * 16 + fr;
    const float bs = bih[en] + bhh[en];
#pragma unroll
    for (int mt = 0; mt < 2; ++mt) {
      const int emb = m0 + wv * 32 + mt * 16 + (lane >> 4) * 4;
#pragma unroll
      for (int r = 0; r < 4; ++r)
        G[(size_t)(emb + r) * G4H + en] = acc[mt][nt][r] + bs;
    }
  }
}

// ---------------------------------------------------------------------------
// Recurrence: one block (512 thr) per 4 batch elements; 64 blocks.
// GEMV lane geometry = R9 (pinned). Batch vectors in LDS as [k*NBAT+i].
// ---------------------------------------------------------------------------
__global__ __launch_bounds__(512, 2) void mann_kernel(
    const float* __restrict__ G, const float* __restrict__ WhhT,
    const float* __restrict__ WrhT, const float* __restrict__ WkaT,
    const float* __restrict__ bka, const float* __restrict__ brh,
    const float* __restrict__ Who, const float* __restrict__ bho,
    const float* __restrict__ Wro, const float* __restrict__ bro,
    float* __restrict__ out)
{
  __shared__ __attribute__((aligned(16))) float M_s[NBAT][NN * MST];   // 90112B
  __shared__ __attribute__((aligned(16))) float h2[HH * NBAT];         // [k*4+i]
  __shared__ __attribute__((aligned(16))) float c2[HH * NBAT];
  __shared__ __attribute__((aligned(16))) float r2[RR * DD * NBAT];    // [m*4+i]
  __shared__ __attribute__((aligned(16))) float brh_s[HH];
  __shared__ float wr_s[NBAT][RR * NN];
  __shared__ float ww_s[NBAT][RR * NN];
  __shared__ float wu_s[NBAT][NN];
  __shared__ float Mn2_s[NBAT][NN];
  __shared__ float kn2_s[NBAT][RR];
  __shared__ __attribute__((aligned(16))) float gates_s[NBAT][G4H];
  __shared__ __attribute__((aligned(16))) float ka_s[NBAT][KAW];
  __shared__ __attribute__((aligned(16))) float bka_s[KAW];
  __shared__ __attribute__((aligned(16))) float Gbuf_s[NBAT][G4H];
  __shared__ float Who_s[NCLS * HH], Wro_s[NCLS * RR * DD], bo_s[NCLS];
  __shared__ int   lu_s[NBAT][RR];

  // Aliases into the gates region (temporally disjoint):
  float*  Kp   = &gates_s[0][0];          // [4][512] wr_t (P8..P12), 2048 fl
  float4* pk1  = (float4*)&gates_s[0][0]; // P1 partials: [i*50+j4], 200 f4
  float4* pk4  = (float4*)&gates_s[0][0]; // P4 partials: [i*81+j4], 324 f4

  const int tid = threadIdx.x;
  const int b0  = blockIdx.x * NBAT;

  // ---- init ----
  for (int e = tid; e < NBAT * NN * MST; e += 512) (&M_s[0][0])[e] = 0.f;
  for (int e = tid; e < NBAT * RR * NN; e += 512) (&wr_s[0][0])[e] = 0.f;
  if (tid < NBAT * NN) (&wu_s[0][0])[tid] = 0.f;
  for (int e = tid; e < HH * NBAT; e += 512) { h2[e] = 0.f; c2[e] = 0.f; }
  for (int e = tid; e < RR * DD * NBAT; e += 512) r2[e] = 0.f;
  if (tid < HH) brh_s[tid] = brh[tid];
  if (tid < KAW) bka_s[tid] = bka[tid];
  for (int e = tid; e < NCLS * HH; e += 512) Who_s[e] = Who[e];
  for (int e = tid; e < NCLS * RR * DD; e += 512) Wro_s[e] = Wro[e];
  if (tid < NCLS) bo_s[tid] = bho[tid] + bro[tid];
  for (int e = tid; e < NBAT * 200; e += 512) {
    const int i = e / 200, o = e - i * 200;
    ((float4*)&Gbuf_s[i][0])[o] =
        ((const float4*)(G + ((size_t)(b0 + i) * TB) * G4H))[o];
  }
  __syncthreads();

  const int ofs1 = (int)((blockIdx.x * 3u) % 10u);
  const int ofs2 = (int)((blockIdx.x * 7u) % 25u);
  const int ofs4 = (int)((blockIdx.x * 5u) % 25u);

#pragma clang loop unroll(disable)
  for (int t = 0; t < TB; ++t) {
    float4 a0v = make_float4(0.f, 0.f, 0.f, 0.f);
    float4 a1v = make_float4(0.f, 0.f, 0.f, 0.f);
    float4 a2v = make_float4(0.f, 0.f, 0.f, 0.f);
    float4 a3v = make_float4(0.f, 0.f, 0.f, 0.f);

    // ---- P1: h += r @ Wrh^T + brh (100 lanes: 50 j4 x 2 k-halves) ----
    if (tid < 100) {
      const int kh = tid / 50, j4 = tid - kh * 50;
      const int kbeg = kh * 80;
      const float4* __restrict__ Wr4 = (const float4*)WrhT + (size_t)kbeg * 50 + j4;
      float4 w0[8], w1[8], w2[8], w3[8];
#define P1_LOAD(B, CH) { const int mm = (CH) * 8; _Pragma("unroll") \
      for (int u = 0; u < 8; ++u) B[u] = Wr4[(mm + u) * 50]; }
#define P1_FMA(B, CH) { const int kb = kbeg + (CH) * 8; _Pragma("unroll") \
      for (int u = 0; u < 8; ++u) { const float4 rk = *(const float4*)&r2[(kb + u) * 4]; \
        a0v.x += rk.x * B[u].x; a0v.y += rk.x * B[u].y; a0v.z += rk.x * B[u].z; a0v.w += rk.x * B[u].w; \
        a1v.x += rk.y * B[u].x; a1v.y += rk.y * B[u].y; a1v.z += rk.y * B[u].z; a1v.w += rk.y * B[u].w; \
        a2v.x += rk.z * B[u].x; a2v.y += rk.z * B[u].y; a2v.z += rk.z * B[u].z; a2v.w += rk.z * B[u].w; \
        a3v.x += rk.w * B[u].x; a3v.y += rk.w * B[u].y; a3v.z += rk.w * B[u].z; a3v.w += rk.w * B[u].w; } }
      PIPE4(10, ofs1, P1_LOAD, P1_FMA)
      if (kh) { pk1[j4] = a0v; pk1[50 + j4] = a1v; pk1[100 + j4] = a2v; pk1[150 + j4] = a3v; }
    }
    __syncthreads();
    if (tid < 50) {
      const float4 p0 = pk1[tid], p1 = pk1[50 + tid];
      const float4 p2 = pk1[100 + tid], p3 = pk1[150 + tid];
      const float4 brv = ((const float4*)brh_s)[tid];
      float4 h0 = *(const float4*)&h2[(4 * tid + 0) * 4];
      float4 h1 = *(const float4*)&h2[(4 * tid + 1) * 4];
      float4 h2v = *(const float4*)&h2[(4 * tid + 2) * 4];
      float4 h3 = *(const float4*)&h2[(4 * tid + 3) * 4];
      h0.x += brv.x + a0v.x + p0.x;  h0.y += brv.x + a1v.x + p1.x;
      h0.z += brv.x + a2v.x + p2.x;  h0.w += brv.x + a3v.x + p3.x;
      h1.x += brv.y + a0v.y + p0.y;  h1.y += brv.y + a1v.y + p1.y;
      h1.z += brv.y + a2v.y + p2.y;  h1.w += brv.y + a3v.y + p3.y;
      h2v.x += brv.z + a0v.z + p0.z; h2v.y += brv.z + a1v.z + p1.z;
      h2v.z += brv.z + a2v.z + p2.z; h2v.w += brv.z + a3v.z + p3.z;
      h3.x += brv.w + a0v.w + p0.w;  h3.y += brv.w + a1v.w + p1.w;
      h3.z += brv.w + a2v.w + p2.w;  h3.w += brv.w + a3v.w + p3.w;
      *(float4*)&h2[(4 * tid + 0) * 4] = h0;
      *(float4*)&h2[(4 * tid + 1) * 4] = h1;
      *(float4*)&h2[(4 * tid + 2) * 4] = h2v;
      *(float4*)&h2[(4 * tid + 3) * 4] = h3;
    }
    __syncthreads();

    // ---- P2: gates = Gbuf + h @ Whh^T (200 lanes x dwordx4, 4 batches) ----
    if (tid < 200) {
      const float4* __restrict__ Wh4 = (const float4*)WhhT + tid;
      float4 g0 = make_float4(0.f, 0.f, 0.f, 0.f);
      float4 g1 = make_float4(0.f, 0.f, 0.f, 0.f);
      float4 g2 = make_float4(0.f, 0.f, 0.f, 0.f);
      float4 g3 = make_float4(0.f, 0.f, 0.f, 0.f);
      float4 w0[8], w1[8], w2[8], w3[8];
#define P2_LOAD(B, CH) { const int kk = (CH) * 8; _Pragma("unroll") \
      for (int u = 0; u < 8; ++u) B[u] = Wh4[(kk + u) * 200]; }
#define P2_FMA(B, CH) { const int kc = (CH) * 8; _Pragma("unroll") \
      for (int u = 0; u < 8; ++u) { const float4 hk = *(const float4*)&h2[(kc + u) * 4]; \
        g0.x += hk.x * B[u].x; g0.y += hk.x * B[u].y; g0.z += hk.x * B[u].z; g0.w += hk.x * B[u].w; \
        g1.x += hk.y * B[u].x; g1.y += hk.y * B[u].y; g1.z += hk.y * B[u].z; g1.w += hk.y * B[u].w; \
        g2.x += hk.z * B[u].x; g2.y += hk.z * B[u].y; g2.z += hk.z * B[u].z; g2.w += hk.z * B[u].w; \
        g3.x += hk.w * B[u].x; g3.y += hk.w * B[u].y; g3.z += hk.w * B[u].z; g3.w += hk.w * B[u].w; } }
      PIPE4(25, ofs2, P2_LOAD, P2_FMA)
      const float4 b0v = *(const float4*)&Gbuf_s[0][4 * tid];
      const float4 b1v = *(const float4*)&Gbuf_s[1][4 * tid];
      const float4 b2v = *(const float4*)&Gbuf_s[2][4 * tid];
      const float4 b3v = *(const float4*)&Gbuf_s[3][4 * tid];
      *(float4*)&gates_s[0][4 * tid] = make_float4(b0v.x + g0.x, b0v.y + g0.y, b0v.z + g0.z, b0v.w + g0.w);
      *(float4*)&gates_s[1][4 * tid] = make_float4(b1v.x + g1.x, b1v.y + g1.y, b1v.z + g1.z, b1v.w + g1.w);
      *(float4*)&gates_s[2][4 * tid] = make_float4(b2v.x + g2.x, b2v.y + g2.y, b2v.z + g2.z, b2v.w + g2.w);
      *(float4*)&gates_s[3][4 * tid] = make_float4(b3v.x + g3.x, b3v.y + g3.y, b3v.z + g3.z, b3v.w + g3.w);
    }
    __syncthreads();

    // ---- P3: LSTM pointwise (800 items, strided) ----
    for (int e = tid; e < NBAT * HH; e += 512) {
      const int i = e / HH, k = e - i * HH;
      const float ig = sigmoidf_(gates_s[i][k]);
      const float fg = sigmoidf_(gates_s[i][HH + k]);
      const float gg = tanhf(gates_s[i][2 * HH + k]);
      const float og = sigmoidf_(gates_s[i][3 * HH + k]);
      const float cn = fg * c2[k * NBAT + i] + ig * gg;
      c2[k * NBAT + i] = cn;
      h2[k * NBAT + i] = og * tanhf(cn);
    }
    __syncthreads();

    // ---- P4: [key|add|sigma] = bka + h @ Wka^T (162 lanes x dwordx4) ;
    //      lanes>=384 prefetch G(t+1) ----
    float4 kav0 = make_float4(0.f, 0.f, 0.f, 0.f);
    float4 kav1 = make_float4(0.f, 0.f, 0.f, 0.f);
    float4 kav2 = make_float4(0.f, 0.f, 0.f, 0.f);
    float4 kav3 = make_float4(0.f, 0.f, 0.f, 0.f);
    if (tid < 162) {
      const int kh = tid / 81, j4 = tid - kh * 81;
      const int kbeg = kh * 100;
      const float4* __restrict__ Wk4 = (const float4*)WkaT + (size_t)kbeg * 81 + j4;
      float4 w0[4], w1[4], w2[4], w3[4];
#define P4_LOAD(B, CH) { const int kk = (CH) * 4; _Pragma("unroll") \
      for (int u = 0; u < 4; ++u) B[u] = Wk4[(kk + u) * 81]; }
#define P4_FMA(B, CH) { const int kc = kbeg + (CH) * 4; _Pragma("unroll") \
      for (int u = 0; u < 4; ++u) { const float4 hk = *(const float4*)&h2[(kc + u) * 4]; \
        kav0.x += hk.x * B[u].x; kav0.y += hk.x * B[u].y; kav0.z += hk.x * B[u].z; kav0.w += hk.x * B[u].w; \
        kav1.x += hk.y * B[u].x; kav1.y += hk.y * B[u].y; kav1.z += hk.y * B[u].z; kav1.w += hk.y * B[u].w; \
        kav2.x += hk.z * B[u].x; kav2.y += hk.z * B[u].y; kav2.z += hk.z * B[u].z; kav2.w += hk.z * B[u].w; \
        kav3.x += hk.w * B[u].x; kav3.y += hk.w * B[u].y; kav3.z += hk.w * B[u].z; kav3.w += hk.w * B[u].w; } }
      PIPE4(25, ofs4, P4_LOAD, P4_FMA)
      if (kh) { pk4[j4] = kav0; pk4[81 + j4] = kav1; pk4[162 + j4] = kav2; pk4[243 + j4] = kav3; }
    } else if (tid >= 384 && t + 1 < TB) {
      for (int idx = tid - 384; idx < NBAT * 200; idx += 128) {
        const int i = idx / 200, o = idx - i * 200;
        ((float4*)&Gbuf_s[i][0])[o] =
            ((const float4*)(G + ((size_t)(b0 + i) * TB + t + 1) * G4H))[o];
      }
    }
    __syncthreads();
    if (tid < 81) {
      const float4 bbv = ((const float4*)bka_s)[tid];
      const float4 p0 = pk4[tid], p1 = pk4[81 + tid];
      const float4 p2 = pk4[162 + tid], p3 = pk4[243 + tid];
      *(float4*)&ka_s[0][4 * tid] = make_float4(kav0.x + p0.x + bbv.x, kav0.y + p0.y + bbv.y,
                                                kav0.z + p0.z + bbv.z, kav0.w + p0.w + bbv.w);
      *(float4*)&ka_s[1][4 * tid] = make_float4(kav1.x + p1.x + bbv.x, kav1.y + p1.y + bbv.y,
                                                kav1.z + p1.z + bbv.z, kav1.w + p1.w + bbv.w);
      *(float4*)&ka_s[2][4 * tid] = make_float4(kav2.x + p2.x + bbv.x, kav2.y + p2.y + bbv.y,
                                                kav2.z + p2.z + bbv.z, kav2.w + p2.w + bbv.w);
      *(float4*)&ka_s[3][4 * tid] = make_float4(kav3.x + p3.x + bbv.x, kav3.y + p3.y + bbv.y,
                                                kav3.z + p3.z + bbv.z, kav3.w + p3.w + bbv.w);
    }
    __syncthreads();

    // ---- P5: least-used select (4 waves, one per batch) + key norms ----
    if (tid < NBAT * 64) {
      const int i = tid >> 6, l = tid & 63;
      unsigned u0v = __float_as_uint(wu_s[i][l]);
      unsigned u1v = __float_as_uint(wu_s[i][l + 64]);
      if (u0v == 0x80000000u) u0v = 0u;
      if (u1v == 0x80000000u) u1v = 0u;
      u0v = (u0v & 0x80000000u) ? ~u0v : (u0v | 0x80000000u);
      u1v = (u1v & 0x80000000u) ? ~u1v : (u1v | 0x80000000u);
      unsigned long long k0 = ((unsigned long long)u0v << 32) | (unsigned)l;
      unsigned long long k1 = ((unsigned long long)u1v << 32) | (unsigned)(l + 64);
#pragma unroll
      for (int rsel = 0; rsel < RR; ++rsel) {
        unsigned long long mn = (k0 < k1) ? k0 : k1;
#pragma unroll
        for (int off = 32; off; off >>= 1) {
          const unsigned long long o = __shfl_xor(mn, off);
          if (o < mn) mn = o;
        }
        const int idx = (int)(mn & 0xFFFFFFFFull);
        if (l == 0) lu_s[i][rsel] = idx;
        if (idx == l)      k0 = ~0ull;
        if (idx == l + 64) k1 = ~0ull;
      }
    } else if (tid < NBAT * 64 + NBAT * RR) {
      const int e = tid - NBAT * 64;
      const int i = e >> 2, q = e & 3;
      float s = 0.f;
#pragma unroll
      for (int d4 = 0; d4 < 10; ++d4) {
        const float4 v = *(const float4*)&ka_s[i][q * DD + 4 * d4];
        s += v.x * v.x + v.y * v.y + v.z * v.z + v.w * v.w;
      }
      kn2_s[i][q] = s;
    }
    __syncthreads();

    // ---- P6: ww = sigma*wr + (1-sigma)*wlu (512 lanes, 4 batches each) ----
    {
      const int n = tid & (NN - 1);
#pragma unroll
      for (int i = 0; i < NBAT; ++i) {
        const float sg = ka_s[i][320];
        const int l0 = lu_s[i][0], l1 = lu_s[i][1], l2 = lu_s[i][2], l3 = lu_s[i][3];
        const float wlu = (n == l0 || n == l1 || n == l2 || n == l3) ? 1.f : 0.f;
        ww_s[i][tid] = sg * wr_s[i][tid] + (1.f - sg) * wlu;
      }
    }
    __syncthreads();

    // ---- P7: M = M*wlu + ww^T @ add ; fused row-norm (512 lanes: i,n) ----
    {
      const int i = tid >> 7, n = tid & (NN - 1);
      const int l0 = lu_s[i][0], l1 = lu_s[i][1], l2 = lu_s[i][2], l3 = lu_s[i][3];
      const float wlu = (n == l0 || n == l1 || n == l2 || n == l3) ? 1.f : 0.f;
      const float wwv0 = ww_s[i][n],          wwv1 = ww_s[i][NN + n];
      const float wwv2 = ww_s[i][2 * NN + n], wwv3 = ww_s[i][3 * NN + n];
      float* Mr = &M_s[i][n * MST];
      const float* Ad = &ka_s[i][160];
      float mn2 = 0.f;
#pragma unroll
      for (int d4 = 0; d4 < 10; ++d4) {
        float4 m = *(const float4*)&Mr[4 * d4];
        m.x *= wlu; m.y *= wlu; m.z *= wlu; m.w *= wlu;
        const float4 av0 = *(const float4*)&Ad[0 * DD + 4 * d4];
        const float4 av1 = *(const float4*)&Ad[1 * DD + 4 * d4];
        const float4 av2 = *(const float4*)&Ad[2 * DD + 4 * d4];
        const float4 av3 = *(const float4*)&Ad[3 * DD + 4 * d4];
        m.x += wwv0 * av0.x + wwv1 * av1.x + wwv2 * av2.x + wwv3 * av3.x;
        m.y += wwv0 * av0.y + wwv1 * av1.y + wwv2 * av2.y + wwv3 * av3.y;
        m.z += wwv0 * av0.z + wwv1 * av1.z + wwv2 * av2.z + wwv3 * av3.z;
        m.w += wwv0 * av0.w + wwv1 * av1.w + wwv2 * av2.w + wwv3 * av3.w;
        *(float4*)&Mr[4 * d4] = m;
        mn2 += m.x * m.x + m.y * m.y + m.z * m.z + m.w * m.w;
      }
      Mn2_s[i][n] = mn2;
    }
    __syncthreads();

    // ---- P8: K = cosine(key, M): 512 lanes = 4 batches x 128 rows, 4 keys ----
    {
      const int i = tid >> 7, n = tid & (NN - 1);
      const float* Mr = &M_s[i][n * MST];
      float s0 = 0.f, s1 = 0.f, s2 = 0.f, s3 = 0.f;
#pragma unroll
      for (int d4 = 0; d4 < 10; ++d4) {
        const float4 mv = *(const float4*)&Mr[4 * d4];
        const float4 k0v = *(const float4*)&ka_s[i][0 * DD + 4 * d4];
        const float4 k1v = *(const float4*)&ka_s[i][1 * DD + 4 * d4];
        const float4 k2v = *(const float4*)&ka_s[i][2 * DD + 4 * d4];
        const float4 k3v = *(const float4*)&ka_s[i][3 * DD + 4 * d4];
        s0 += k0v.x * mv.x + k0v.y * mv.y + k0v.z * mv.z + k0v.w * mv.w;
        s1 += k1v.x * mv.x + k1v.y * mv.y + k1v.z * mv.z + k1v.w * mv.w;
        s2 += k2v.x * mv.x + k2v.y * mv.y + k2v.z * mv.z + k2v.w * mv.w;
        s3 += k3v.x * mv.x + k3v.y * mv.y + k3v.z * mv.z + k3v.w * mv.w;
      }
      const float mn2 = Mn2_s[i][n];
      Kp[(i << 9) + 0 * NN + n] = s0 / sqrtf(kn2_s[i][0] * mn2 + 1e-6f);
      Kp[(i << 9) + 1 * NN + n] = s1 / sqrtf(kn2_s[i][1] * mn2 + 1e-6f);
      Kp[(i << 9) + 2 * NN + n] = s2 / sqrtf(kn2_s[i][2] * mn2 + 1e-6f);
      Kp[(i << 9) + 3 * NN + n] = s3 / sqrtf(kn2_s[i][3] * mn2 + 1e-6f);
    }
    __syncthreads();

    // ---- P9: softmax over N (16 rows, 2 per wave) ----
    {
      const int w = tid >> 6, l = tid & 63;
#pragma unroll
      for (int rr = 0; rr < 2; ++rr) {
        const int row = w * 2 + rr;           // 0..15
        float* Kr = Kp + ((row >> 2) << 9) + (row & 3) * NN;
        const float v0 = Kr[l], v1 = Kr[l + 64];
        float mx = fmaxf(v0, v1);
#pragma unroll
        for (int off = 32; off; off >>= 1) mx = fmaxf(mx, __shfl_xor(mx, off));
        const float e0 = expf(v0 - mx), e1 = expf(v1 - mx);
        float s = e0 + e1;
#pragma unroll
        for (int off = 32; off; off >>= 1) s += __shfl_xor(s, off);
        const float inv = 1.f / s;
        Kr[l] = e0 * inv; Kr[l + 64] = e1 * inv;
      }
    }
    __syncthreads();

    // ---- P10: r = wr_t @ M (160 lanes) ; P11: wu (lanes 160+, strided) ----
    if (tid < NBAT * RR * 10) {
      const int i = tid / (RR * 10), rem = tid - i * (RR * 10);
      const int q = rem / 10, d4 = rem - q * 10;
      const float* Kr = Kp + (i << 9) + q * NN;
      const float* Mb = &M_s[i][4 * d4];
      float4 acc = make_float4(0.f, 0.f, 0.f, 0.f);
      for (int n = 0; n < NN; ++n) {
        const float kw = Kr[n];
        const float4 mv = *(const float4*)&Mb[n * MST];
        acc.x += kw * mv.x; acc.y += kw * mv.y;
        acc.z += kw * mv.z; acc.w += kw * mv.w;
      }
      const int dbase = (q * DD + 4 * d4) * NBAT + i;
      r2[dbase]            = acc.x;
      r2[dbase + NBAT]     = acc.y;
      r2[dbase + 2 * NBAT] = acc.z;
      r2[dbase + 3 * NBAT] = acc.w;
    } else {
      for (int e = tid - NBAT * RR * 10; e < NBAT * NN; e += 512 - NBAT * RR * 10) {
        const int i = e >> 7, n = e & (NN - 1);
        float s = 0.95f * wu_s[i][n];
#pragma unroll
        for (int q = 0; q < RR; ++q)
          s += Kp[(i << 9) + q * NN + n] + ww_s[i][q * NN + n];
        wu_s[i][n] = s;
      }
    }
    __syncthreads();

    // ---- P12: out (waves 0-3) ; wr <- wr_t (waves 4-7) ----
    if (tid < NBAT * 64) {
      const int i = tid >> 6, l = tid & 63;
      const size_t ob = ((size_t)(b0 + i) * TB + t) * NCLS;
#pragma unroll
      for (int j = 0; j < NCLS; ++j) {
        float p = 0.f;
        for (int k = l; k < HH; k += 64)      p += h2[k * NBAT + i] * Who_s[j * HH + k];
        for (int m = l; m < RR * DD; m += 64) p += r2[m * NBAT + i] * Wro_s[j * RR * DD + m];
#pragma unroll
        for (int off = 32; off; off >>= 1) p += __shfl_xor(p, off);
        if (l == 0) out[ob + j] = p + bo_s[j];
      }
    } else {
      for (int f = tid - 256; f < NBAT * RR * NN; f += 256) (&wr_s[0][0])[f] = Kp[f];
    }
    __syncthreads();
  }
}

// ---------------------------------------------------------------------------
extern "C" void kernel_launch(void* const* d_in, const int* in_sizes, int n_in,
                              void* d_out, int out_size, void* d_ws, size_t ws_size,
                              hipStream_t stream) {
  const float* x    = (const float*)d_in[0];
  const float* Wkey = (const float*)d_in[1];
  const float* bkey = (const float*)d_in[2];
  const float* Wadd = (const float*)d_in[3];
  const float* badd = (const float*)d_in[4];
  const float* Wsig = (const float*)d_in[5];
  const float* bsig = (const float*)d_in[6];
  const float* Who  = (const float*)d_in[7];
  const float* bho  = (const float*)d_in[8];
  const float* Wro  = (const float*)d_in[9];
  const float* bro  = (const float*)d_in[10];
  const float* Wrh  = (const float*)d_in[11];
  const float* brh  = (const float*)d_in[12];
  const float* Wih  = (const float*)d_in[13];
  const float* bih  = (const float*)d_in[14];
  const float* Whh  = (const float*)d_in[15];
  const float* bhh  = (const float*)d_in[16];

  float* ws   = (float*)d_ws;
  float* G    = ws;                       // 25600*800
  float* WhhT = G + (size_t)25600 * 800;  // 160,000
  float* WrhT = WhhT + 160000;            // 32,000
  float* WkaT = WrhT + 32000;             // 64,800
  float* bka  = WkaT + 64800;             // 324

  prep_kernel<<<(160000 + 255) / 256, 256, 0, stream>>>(
      Whh, Wrh, Wkey, Wadd, Wsig, bkey, badd, bsig, WhhT, WrhT, WkaT, bka);

  dim3 gA(G4H / GN, 25600 / GM);   // (10, 200)
  gemm_in2_kernel<<<gA, 256, 0, stream>>>(x, Wih, bih, bhh, G);

  mann_kernel<<<NBLK, 512, 0, stream>>>(G, WhhT, WrhT, WkaT, bka, brh,
                                        Who, bho, Wro, bro, (float*)d_out);
}

// Round 10
// 2829.840 us; speedup vs baseline: 1.2189x; 1.2189x over previous
//
// MANN/NTM forward — R19: revert to R17 (best, 2890µs) + LDS-local-phase opts.
// R18 post-mortem: NBAT amortization can't cut wall time (batches already
// fully parallel; fatter blocks only raise per-step latency). NBAT=2 pinned.
// Changes vs R17 (global weight-stream geometry untouched — pinned R11-R16):
//  1. P6 fused into P7 (ww inline; -1 phase, -1 barrier).
//  2. P10 4-way n-split: 320 lanes x 32 iters + shfl reduce (was 80 x 128
//     serial LDS chain); wu update moved to lanes 320+.
#include <hip/hip_runtime.h>
#include <math.h>

#define TB   100
#define BB   256
#define INF_ 784
#define HH   200
#define RR   4
#define NN   128
#define DD   40
#define NCLS 5
#define G4H  800   // 4*H
#define KAW  324   // 160 key + 160 add + 1 sigma + 3 pad
#define MST  44    // padded M row stride
#define NBAT 2     // batches per block
#define NBLK (BB / NBAT)

typedef __attribute__((ext_vector_type(8))) short bf16x8;
typedef __attribute__((ext_vector_type(4))) float f32x4;

__device__ __forceinline__ float sigmoidf_(float x) { return 1.0f / (1.0f + expf(-x)); }

__device__ __forceinline__ void splitbf_(float v, unsigned short &hi, unsigned short &lo) {
  const unsigned b = __float_as_uint(v);
  hi = (unsigned short)(b >> 16);
  const float hf = __uint_as_float(b & 0xFFFF0000u);
  lo = (unsigned short)(__float_as_uint(v - hf) >> 16);
}

#define ADV(c, CC) { ++(c); if ((c) == (CC)) (c) = 0; }

// 4-slot rotating software pipeline (3 chunks of loads in flight ahead of FMA).
#define PIPE4(CC, OFS, LOADM, FMAM)                                     \
  {                                                                     \
    int chL = (OFS), chF = (OFS);                                       \
    LOADM(w0, chL); ADV(chL, CC); LOADM(w1, chL); ADV(chL, CC);         \
    LOADM(w2, chL); ADV(chL, CC);                                       \
    _Pragma("unroll 1")                                                 \
    for (int g = 0; g < ((CC) - 3) / 4; ++g) {                          \
      LOADM(w3, chL); ADV(chL, CC); FMAM(w0, chF); ADV(chF, CC);        \
      LOADM(w0, chL); ADV(chL, CC); FMAM(w1, chF); ADV(chF, CC);        \
      LOADM(w1, chL); ADV(chL, CC); FMAM(w2, chF); ADV(chF, CC);        \
      LOADM(w2, chL); ADV(chL, CC); FMAM(w3, chF); ADV(chF, CC);        \
    }                                                                   \
    {                                                                   \
      constexpr int REMX = (CC) - 3 - 4 * (((CC) - 3) / 4);             \
      if (REMX >= 1) { LOADM(w3, chL); ADV(chL, CC); }                  \
      FMAM(w0, chF); ADV(chF, CC);                                      \
      if (REMX >= 2) { LOADM(w0, chL); ADV(chL, CC); }                  \
      FMAM(w1, chF); ADV(chF, CC);                                      \
      if (REMX >= 3) { LOADM(w1, chL); ADV(chL, CC); }                  \
      FMAM(w2, chF); ADV(chF, CC);                                      \
      if (REMX >= 1) { FMAM(w3, chF); ADV(chF, CC); }                   \
      if (REMX >= 2) { FMAM(w0, chF); ADV(chF, CC); }                   \
      if (REMX >= 3) { FMAM(w1, chF); ADV(chF, CC); }                   \
    }                                                                   \
  }

// ---------------------------------------------------------------------------
// Prep: transpose weights into GEMV-friendly (k-major) layouts in workspace.
// ---------------------------------------------------------------------------
__global__ __launch_bounds__(256) void prep_kernel(
    const float* __restrict__ Whh, const float* __restrict__ Wrh,
    const float* __restrict__ Wkey, const float* __restrict__ Wadd,
    const float* __restrict__ Wsig, const float* __restrict__ bkey,
    const float* __restrict__ badd, const float* __restrict__ bsig,
    float* __restrict__ WhhT, float* __restrict__ WrhT,
    float* __restrict__ WkaT, float* __restrict__ bka)
{
  const int tid = blockIdx.x * 256 + threadIdx.x;
  if (tid < 160000) {            // Whh (800,200) -> WhhT (200,800)
    const int j = tid / 200, k = tid - j * 200;
    WhhT[k * G4H + j] = Whh[tid];
  }
  if (tid < 32000) {             // Wrh (200,160) -> WrhT (160,200)
    const int k = tid / 160, m = tid - k * 160;
    WrhT[m * HH + k] = Wrh[tid];
  }
  if (tid < 200 * KAW) {         // [Wkey(160,200)|Wadd(160,200)|Wsig(1,200)]^T
    const int k = tid / KAW, j = tid - k * KAW;
    float v = 0.0f;
    if (j < 160)       v = Wkey[j * HH + k];
    else if (j < 320)  v = Wadd[(j - 160) * HH + k];
    else if (j == 320) v = Wsig[k];
    WkaT[tid] = v;
  }
  if (tid < KAW) {
    float v = 0.0f;
    if (tid < 160)       v = bkey[tid];
    else if (tid < 320)  v = badd[tid - 160];
    else if (tid == 320) v = bsig[0];
    bka[tid] = v;
  }
}

// ---------------------------------------------------------------------------
// gemm_in2: G[m,j] = sum_k x[m,k]*Wih[j,k] + bih[j] + bhh[j]  (MFMA bf16,
// split-precision hi/lo). Tile 128(M) x 80(N), 256 thr = 4 waves, K-step 32.
// ---------------------------------------------------------------------------
#define GM  128
#define GN  80
#define LDK 40   // padded K stride in bf16 elems (80B, 16B-aligned rows)

__global__ __launch_bounds__(256) void gemm_in2_kernel(
    const float* __restrict__ X, const float* __restrict__ Wih,
    const float* __restrict__ bih, const float* __restrict__ bhh,
    float* __restrict__ G)
{
  __shared__ __attribute__((aligned(16))) unsigned short Ahi[GM][LDK];
  __shared__ __attribute__((aligned(16))) unsigned short Alo[GM][LDK];
  __shared__ __attribute__((aligned(16))) unsigned short Bhi[GN][LDK];
  __shared__ __attribute__((aligned(16))) unsigned short Blo[GN][LDK];

  const int tid  = threadIdx.x;
  const int wv   = tid >> 6, lane = tid & 63;
  const int n0   = blockIdx.x * GN;
  const int m0   = blockIdx.y * GM;

  f32x4 acc[2][5];
#pragma unroll
  for (int mt = 0; mt < 2; ++mt)
#pragma unroll
    for (int nt = 0; nt < 5; ++nt) acc[mt][nt] = (f32x4){0.f, 0.f, 0.f, 0.f};

  const int arow = tid >> 1, ak = (tid & 1) * 16;
  const float* Ap = X + (size_t)(m0 + arow) * INF_ + ak;
  const float* Bp = Wih + (size_t)(n0 + arow) * INF_ + ak;  // arow<80 when tid<160

  const int fr = lane & 15, fk = (lane >> 4) * 8;

  for (int kk = 0; kk < 800; kk += 32) {
    // ---- global loads (zero-padded past K=784; 784%16==0 so per-16 guard) ----
    float va[16], vb[16];
    const bool av = (kk + ak) < INF_;
#pragma unroll
    for (int i = 0; i < 16; ++i) va[i] = 0.f;
    if (av) {
      *(float4*)&va[0]  = *(const float4*)(Ap + kk);
      *(float4*)&va[4]  = *(const float4*)(Ap + kk + 4);
      *(float4*)&va[8]  = *(const float4*)(Ap + kk + 8);
      *(float4*)&va[12] = *(const float4*)(Ap + kk + 12);
    }
    if (tid < 160) {
#pragma unroll
      for (int i = 0; i < 16; ++i) vb[i] = 0.f;
      if (av) {
        *(float4*)&vb[0]  = *(const float4*)(Bp + kk);
        *(float4*)&vb[4]  = *(const float4*)(Bp + kk + 4);
        *(float4*)&vb[8]  = *(const float4*)(Bp + kk + 8);
        *(float4*)&vb[12] = *(const float4*)(Bp + kk + 12);
      }
    }
    __syncthreads();   // prior compute done before LDS overwrite
    // ---- convert + store to LDS ----
    {
      unsigned ah[8], al[8];
#pragma unroll
      for (int i = 0; i < 8; ++i) {
        unsigned short h0, l0, h1, l1;
        splitbf_(va[2 * i], h0, l0);
        splitbf_(va[2 * i + 1], h1, l1);
        ah[i] = (unsigned)h0 | ((unsigned)h1 << 16);
        al[i] = (unsigned)l0 | ((unsigned)l1 << 16);
      }
      ((int4*)&Ahi[arow][ak])[0] = make_int4(ah[0], ah[1], ah[2], ah[3]);
      ((int4*)&Ahi[arow][ak + 8])[0] = make_int4(ah[4], ah[5], ah[6], ah[7]);
      ((int4*)&Alo[arow][ak])[0] = make_int4(al[0], al[1], al[2], al[3]);
      ((int4*)&Alo[arow][ak + 8])[0] = make_int4(al[4], al[5], al[6], al[7]);
    }
    if (tid < 160) {
      unsigned bh[8], bl[8];
#pragma unroll
      for (int i = 0; i < 8; ++i) {
        unsigned short h0, l0, h1, l1;
        splitbf_(vb[2 * i], h0, l0);
        splitbf_(vb[2 * i + 1], h1, l1);
        bh[i] = (unsigned)h0 | ((unsigned)h1 << 16);
        bl[i] = (unsigned)l0 | ((unsigned)l1 << 16);
      }
      ((int4*)&Bhi[arow][ak])[0] = make_int4(bh[0], bh[1], bh[2], bh[3]);
      ((int4*)&Bhi[arow][ak + 8])[0] = make_int4(bh[4], bh[5], bh[6], bh[7]);
      ((int4*)&Blo[arow][ak])[0] = make_int4(bl[0], bl[1], bl[2], bl[3]);
      ((int4*)&Blo[arow][ak + 8])[0] = make_int4(bl[4], bl[5], bl[6], bl[7]);
    }
    __syncthreads();
    // ---- MFMA: 2 m-tiles x 5 n-tiles x 3 passes ----
    const bf16x8 a0h = *(const bf16x8*)&Ahi[wv * 32 + fr][fk];
    const bf16x8 a0l = *(const bf16x8*)&Alo[wv * 32 + fr][fk];
    const bf16x8 a1h = *(const bf16x8*)&Ahi[wv * 32 + 16 + fr][fk];
    const bf16x8 a1l = *(const bf16x8*)&Alo[wv * 32 + 16 + fr][fk];
#pragma unroll
    for (int nt = 0; nt < 5; ++nt) {
      const bf16x8 bh = *(const bf16x8*)&Bhi[nt * 16 + fr][fk];
      const bf16x8 bl = *(const bf16x8*)&Blo[nt * 16 + fr][fk];
      acc[0][nt] = __builtin_amdgcn_mfma_f32_16x16x32_bf16(a0h, bh, acc[0][nt], 0, 0, 0);
      acc[1][nt] = __builtin_amdgcn_mfma_f32_16x16x32_bf16(a1h, bh, acc[1][nt], 0, 0, 0);
      acc[0][nt] = __builtin_amdgcn_mfma_f32_16x16x32_bf16(a0l, bh, acc[0][nt], 0, 0, 0);
      acc[1][nt] = __builtin_amdgcn_mfma_f32_16x16x32_bf16(a1l, bh, acc[1][nt], 0, 0, 0);
      acc[0][nt] = __builtin_amdgcn_mfma_f32_16x16x32_bf16(a0h, bl, acc[0][nt], 0, 0, 0);
      acc[1][nt] = __builtin_amdgcn_mfma_f32_16x16x32_bf16(a1h, bl, acc[1][nt], 0, 0, 0);
    }
  }

  // ---- epilogue: D col = lane&15, row = (lane>>4)*4 + reg ----
#pragma unroll
  for (int nt = 0; nt < 5; ++nt) {
    const int en = n0 + nt * 16 + fr;
    const float bs = bih[en] + bhh[en];
#pragma unroll
    for (int mt = 0; mt < 2; ++mt) {
      const int emb = m0 + wv * 32 + mt * 16 + (lane >> 4) * 4;
#pragma unroll
      for (int r = 0; r < 4; ++r)
        G[(size_t)(emb + r) * G4H + en] = acc[mt][nt][r] + bs;
    }
  }
}

// ---------------------------------------------------------------------------
// Recurrence: one block (512 thr) per 2 batch elements; 128 blocks.
// Global weight-stream geometry FROZEN at R9. LDS-local phases optimized.
// ---------------------------------------------------------------------------
__global__ __launch_bounds__(512, 2) void mann_kernel(
    const float* __restrict__ G, const float* __restrict__ WhhT,
    const float* __restrict__ WrhT, const float* __restrict__ WkaT,
    const float* __restrict__ bka, const float* __restrict__ brh,
    const float* __restrict__ Who, const float* __restrict__ bho,
    const float* __restrict__ Wro, const float* __restrict__ bro,
    float* __restrict__ out)
{
  __shared__ __attribute__((aligned(16))) float M_s[NBAT][NN * MST];
  __shared__ __attribute__((aligned(16))) float h2[HH * NBAT];   // [k*2+i]
  __shared__ __attribute__((aligned(16))) float c2[HH * NBAT];
  __shared__ __attribute__((aligned(16))) float r2[RR * DD * NBAT];
  __shared__ __attribute__((aligned(16))) float brh_s[HH];
  __shared__ float wr_s[NBAT][RR * NN];
  __shared__ float ww_s[NBAT][RR * NN];
  __shared__ float wu_s[NBAT][NN];
  __shared__ float Mn2_s[NBAT][NN];
  __shared__ float kn2_s[NBAT][RR];
  __shared__ __attribute__((aligned(16))) float gates_s[NBAT][G4H];
  __shared__ __attribute__((aligned(16))) float ka_s[NBAT][KAW];
  __shared__ __attribute__((aligned(16))) float bka_s[KAW];
  __shared__ __attribute__((aligned(16))) float Gbuf_s[NBAT][G4H];
  __shared__ float Who_s[NCLS * HH], Wro_s[NCLS * RR * DD], bo_s[NCLS];
  __shared__ int   lu_s[NBAT][RR];

  // Aliases into the gates region (temporally disjoint):
  float*  Kp   = &gates_s[0][0];          // [2][512] wr_t (P8..P12)
  float4* pkA4 = (float4*)&gates_s[0][0]; // P1 partials batch0 (50 float4)
  float4* pkB4 = pkA4 + 50;               // P1 partials batch1
  float4* pka4 = (float4*)&gates_s[0][0]; // P4 partials: [0..80]=b0, [81..161]=b1

  const int tid = threadIdx.x;
  const int b0  = blockIdx.x * NBAT;

  // ---- init ----
  for (int e = tid; e < NBAT * NN * MST; e += 512) (&M_s[0][0])[e] = 0.f;
  for (int e = tid; e < NBAT * RR * NN; e += 512) (&wr_s[0][0])[e] = 0.f;
  if (tid < NBAT * NN) (&wu_s[0][0])[tid] = 0.f;
  for (int e = tid; e < HH * NBAT; e += 512) { h2[e] = 0.f; c2[e] = 0.f; }
  if (tid < RR * DD * NBAT) r2[tid] = 0.f;
  if (tid < HH) brh_s[tid] = brh[tid];
  if (tid < KAW) bka_s[tid] = bka[tid];
  for (int e = tid; e < NCLS * HH; e += 512) Who_s[e] = Who[e];
  for (int e = tid; e < NCLS * RR * DD; e += 512) Wro_s[e] = Wro[e];
  if (tid < NCLS) bo_s[tid] = bho[tid] + bro[tid];
  if (tid < NBAT * 200) {
    const int i = tid / 200, o = tid - i * 200;
    ((float4*)&Gbuf_s[i][0])[o] =
        ((const float4*)(G + ((size_t)(b0 + i) * TB) * G4H))[o];
  }
  __syncthreads();

  const int ofs1 = (int)((blockIdx.x * 3u) % 10u);
  const int ofs2 = (int)((blockIdx.x * 7u) % 25u);
  const int ofs4 = (int)((blockIdx.x * 5u) % 25u);

#pragma clang loop unroll(disable)
  for (int t = 0; t < TB; ++t) {
    float4 a0v = make_float4(0.f, 0.f, 0.f, 0.f);
    float4 a1v = make_float4(0.f, 0.f, 0.f, 0.f);

    // ---- P1: h += r @ Wrh^T + brh (100 lanes: 50 j4 x 2 k-halves, dwordx4) ----
    if (tid < 100) {
      const int kh = tid / 50, j4 = tid - kh * 50;
      const int kbeg = kh * 80;
      const float4* __restrict__ Wr4 = (const float4*)WrhT + (size_t)kbeg * 50 + j4;
      float4 w0[8], w1[8], w2[8], w3[8];
#define P1_LOAD(B, CH) { const int mm = (CH) * 8; _Pragma("unroll") \
      for (int u = 0; u < 8; ++u) B[u] = Wr4[(mm + u) * 50]; }
#define P1_FMA(B, CH) { const int kb = kbeg + (CH) * 8; _Pragma("unroll") \
      for (int u = 0; u < 8; ++u) { const float2 rk = *(const float2*)&r2[(kb + u) * 2]; \
        a0v.x += rk.x * B[u].x; a0v.y += rk.x * B[u].y; a0v.z += rk.x * B[u].z; a0v.w += rk.x * B[u].w; \
        a1v.x += rk.y * B[u].x; a1v.y += rk.y * B[u].y; a1v.z += rk.y * B[u].z; a1v.w += rk.y * B[u].w; } }
      PIPE4(10, ofs1, P1_LOAD, P1_FMA)
      if (kh) { pkA4[j4] = a0v; pkB4[j4] = a1v; }
    }
    __syncthreads();
    if (tid < 50) {
      const int j4 = tid;
      const float4 pA = pkA4[j4], pB = pkB4[j4];
      const float4 brv = ((const float4*)brh_s)[j4];
      float4 hv0 = *(const float4*)&h2[8 * j4];
      float4 hv1 = *(const float4*)&h2[8 * j4 + 4];
      hv0.x += brv.x + a0v.x + pA.x;  hv0.y += brv.x + a1v.x + pB.x;
      hv0.z += brv.y + a0v.y + pA.y;  hv0.w += brv.y + a1v.y + pB.y;
      hv1.x += brv.z + a0v.z + pA.z;  hv1.y += brv.z + a1v.z + pB.z;
      hv1.z += brv.w + a0v.w + pA.w;  hv1.w += brv.w + a1v.w + pB.w;
      *(float4*)&h2[8 * j4]     = hv0;
      *(float4*)&h2[8 * j4 + 4] = hv1;
    }
    __syncthreads();

    // ---- P2: gates = Gbuf + h @ Whh^T (200 lanes x dwordx4, 2 batches) ----
    if (tid < 200) {
      const float4* __restrict__ Wh4 = (const float4*)WhhT + tid;
      float4 g0 = *(const float4*)&Gbuf_s[0][4 * tid];
      float4 g1 = *(const float4*)&Gbuf_s[1][4 * tid];
      float4 w0[8], w1[8], w2[8], w3[8];
#define P2_LOAD(B, CH) { const int kk = (CH) * 8; _Pragma("unroll") \
      for (int u = 0; u < 8; ++u) B[u] = Wh4[(kk + u) * 200]; }
#define P2_FMA(B, CH) { const int kc = (CH) * 8; _Pragma("unroll") \
      for (int u = 0; u < 8; ++u) { const float2 hk = *(const float2*)&h2[(kc + u) * 2]; \
        g0.x += hk.x * B[u].x; g0.y += hk.x * B[u].y; g0.z += hk.x * B[u].z; g0.w += hk.x * B[u].w; \
        g1.x += hk.y * B[u].x; g1.y += hk.y * B[u].y; g1.z += hk.y * B[u].z; g1.w += hk.y * B[u].w; } }
      PIPE4(25, ofs2, P2_LOAD, P2_FMA)
      *(float4*)&gates_s[0][4 * tid] = g0;
      *(float4*)&gates_s[1][4 * tid] = g1;
    }
    __syncthreads();

    // ---- P3: LSTM pointwise (400 items) ----
    if (tid < NBAT * HH) {
      const int i = tid / HH, k = tid - i * HH;
      const float ig = sigmoidf_(gates_s[i][k]);
      const float fg = sigmoidf_(gates_s[i][HH + k]);
      const float gg = tanhf(gates_s[i][2 * HH + k]);
      const float og = sigmoidf_(gates_s[i][3 * HH + k]);
      const float cn = fg * c2[k * NBAT + i] + ig * gg;
      c2[k * NBAT + i] = cn;
      h2[k * NBAT + i] = og * tanhf(cn);
    }
    __syncthreads();

    // ---- P4: [key|add|sigma] = bka + h @ Wka^T (162 lanes x dwordx4) ;
    //      lanes>=384 prefetch G(t+1) ----
    float4 kav0 = make_float4(0.f, 0.f, 0.f, 0.f);
    float4 kav1 = make_float4(0.f, 0.f, 0.f, 0.f);
    if (tid < 162) {
      const int kh = tid / 81, j4 = tid - kh * 81;
      const int kbeg = kh * 100;
      const float4* __restrict__ Wk4 = (const float4*)WkaT + (size_t)kbeg * 81 + j4;
      float4 w0[4], w1[4], w2[4], w3[4];
#define P4_LOAD(B, CH) { const int kk = (CH) * 4; _Pragma("unroll") \
      for (int u = 0; u < 4; ++u) B[u] = Wk4[(kk + u) * 81]; }
#define P4_FMA(B, CH) { const int kc = kbeg + (CH) * 4; _Pragma("unroll") \
      for (int u = 0; u < 4; ++u) { const float2 hk = *(const float2*)&h2[(kc + u) * 2]; \
        kav0.x += hk.x * B[u].x; kav0.y += hk.x * B[u].y; kav0.z += hk.x * B[u].z; kav0.w += hk.x * B[u].w; \
        kav1.x += hk.y * B[u].x; kav1.y += hk.y * B[u].y; kav1.z += hk.y * B[u].z; kav1.w += hk.y * B[u].w; } }
      PIPE4(25, ofs4, P4_LOAD, P4_FMA)
      if (kh) { pka4[j4] = kav0; pka4[81 + j4] = kav1; }
    } else if (tid >= 384 && t + 1 < TB) {
      for (int idx = tid - 384; idx < NBAT * 200; idx += 128) {
        const int i = idx / 200, o = idx - i * 200;
        ((float4*)&Gbuf_s[i][0])[o] =
            ((const float4*)(G + ((size_t)(b0 + i) * TB + t + 1) * G4H))[o];
      }
    }
    __syncthreads();
    if (tid < 81) {
      const float4 bbv = ((const float4*)bka_s)[tid];
      const float4 p0 = pka4[tid], p1 = pka4[81 + tid];
      float4 v0, v1;
      v0.x = kav0.x + p0.x + bbv.x; v0.y = kav0.y + p0.y + bbv.y;
      v0.z = kav0.z + p0.z + bbv.z; v0.w = kav0.w + p0.w + bbv.w;
      v1.x = kav1.x + p1.x + bbv.x; v1.y = kav1.y + p1.y + bbv.y;
      v1.z = kav1.z + p1.z + bbv.z; v1.w = kav1.w + p1.w + bbv.w;
      *(float4*)&ka_s[0][4 * tid] = v0;
      *(float4*)&ka_s[1][4 * tid] = v1;
    }
    __syncthreads();

    // ---- P5: least-used select (waves 0-1, one per batch) + key norms ----
    if (tid < NBAT * 64) {
      const int i = tid >> 6, l = tid & 63;
      unsigned u0v = __float_as_uint(wu_s[i][l]);
      unsigned u1v = __float_as_uint(wu_s[i][l + 64]);
      if (u0v == 0x80000000u) u0v = 0u;
      if (u1v == 0x80000000u) u1v = 0u;
      u0v = (u0v & 0x80000000u) ? ~u0v : (u0v | 0x80000000u);
      u1v = (u1v & 0x80000000u) ? ~u1v : (u1v | 0x80000000u);
      unsigned long long k0 = ((unsigned long long)u0v << 32) | (unsigned)l;
      unsigned long long k1 = ((unsigned long long)u1v << 32) | (unsigned)(l + 64);
#pragma unroll
      for (int rsel = 0; rsel < RR; ++rsel) {
        unsigned long long mn = (k0 < k1) ? k0 : k1;
#pragma unroll
        for (int off = 32; off; off >>= 1) {
          const unsigned long long o = __shfl_xor(mn, off);
          if (o < mn) mn = o;
        }
        const int idx = (int)(mn & 0xFFFFFFFFull);
        if (l == 0) lu_s[i][rsel] = idx;
        if (idx == l)      k0 = ~0ull;
        if (idx == l + 64) k1 = ~0ull;
      }
    } else if (tid < NBAT * 64 + NBAT * RR) {
      const int e = tid - NBAT * 64;
      const int i = e >> 2, q = e & 3;
      float s = 0.f;
#pragma unroll
      for (int d4 = 0; d4 < 10; ++d4) {
        const float4 v = *(const float4*)&ka_s[i][q * DD + 4 * d4];
        s += v.x * v.x + v.y * v.y + v.z * v.z + v.w * v.w;
      }
      kn2_s[i][q] = s;
    }
    __syncthreads();

    // ---- P7 (P6 fused): ww inline; M = M*wlu + ww^T @ add ; row-norm ----
    if (tid < NBAT * NN) {
      const int i = tid >> 7, n = tid & (NN - 1);
      const int l0 = lu_s[i][0], l1 = lu_s[i][1], l2 = lu_s[i][2], l3 = lu_s[i][3];
      const float wlu = (n == l0 || n == l1 || n == l2 || n == l3) ? 1.f : 0.f;
      const float sg = ka_s[i][320];
      const float oms = (1.f - sg) * wlu;
      const float wwv0 = sg * wr_s[i][n]          + oms;
      const float wwv1 = sg * wr_s[i][NN + n]     + oms;
      const float wwv2 = sg * wr_s[i][2 * NN + n] + oms;
      const float wwv3 = sg * wr_s[i][3 * NN + n] + oms;
      ww_s[i][n]          = wwv0;
      ww_s[i][NN + n]     = wwv1;
      ww_s[i][2 * NN + n] = wwv2;
      ww_s[i][3 * NN + n] = wwv3;
      float* Mr = &M_s[i][n * MST];
      const float* Ad = &ka_s[i][160];
      float mn2 = 0.f;
#pragma unroll
      for (int d4 = 0; d4 < 10; ++d4) {
        float4 m = *(const float4*)&Mr[4 * d4];
        m.x *= wlu; m.y *= wlu; m.z *= wlu; m.w *= wlu;
        const float4 av0 = *(const float4*)&Ad[0 * DD + 4 * d4];
        const float4 av1 = *(const float4*)&Ad[1 * DD + 4 * d4];
        const float4 av2 = *(const float4*)&Ad[2 * DD + 4 * d4];
        const float4 av3 = *(const float4*)&Ad[3 * DD + 4 * d4];
        m.x += wwv0 * av0.x + wwv1 * av1.x + wwv2 * av2.x + wwv3 * av3.x;
        m.y += wwv0 * av0.y + wwv1 * av1.y + wwv2 * av2.y + wwv3 * av3.y;
        m.z += wwv0 * av0.z + wwv1 * av1.z + wwv2 * av2.z + wwv3 * av3.z;
        m.w += wwv0 * av0.w + wwv1 * av1.w + wwv2 * av2.w + wwv3 * av3.w;
        *(float4*)&Mr[4 * d4] = m;
        mn2 += m.x * m.x + m.y * m.y + m.z * m.z + m.w * m.w;
      }
      Mn2_s[i][n] = mn2;
    }
    __syncthreads();

    // ---- P8: K = cosine(key, M): 512 lanes, each reads one M row, 2 keys ----
    {
      const int i = tid >> 8, qq = (tid >> 7) & 1, n = tid & (NN - 1);
      const float* Mr = &M_s[i][n * MST];
      const float* Ky0 = &ka_s[i][qq * DD];
      const float* Ky1 = &ka_s[i][(qq + 2) * DD];
      float s0 = 0.f, s1 = 0.f;
#pragma unroll
      for (int d4 = 0; d4 < 10; ++d4) {
        const float4 mv = *(const float4*)&Mr[4 * d4];
        const float4 k0v = *(const float4*)&Ky0[4 * d4];
        const float4 k1v = *(const float4*)&Ky1[4 * d4];
        s0 += k0v.x * mv.x + k0v.y * mv.y + k0v.z * mv.z + k0v.w * mv.w;
        s1 += k1v.x * mv.x + k1v.y * mv.y + k1v.z * mv.z + k1v.w * mv.w;
      }
      const float mn2 = Mn2_s[i][n];
      Kp[(i << 9) + qq * NN + n]       = s0 / sqrtf(kn2_s[i][qq] * mn2 + 1e-6f);
      Kp[(i << 9) + (qq + 2) * NN + n] = s1 / sqrtf(kn2_s[i][qq + 2] * mn2 + 1e-6f);
    }
    __syncthreads();

    // ---- P9: softmax over N (8 rows, one per wave) ----
    {
      const int w = tid >> 6, l = tid & 63;
      float* Kr = Kp + ((w >> 2) << 9) + (w & 3) * NN;
      const float v0 = Kr[l], v1 = Kr[l + 64];
      float mx = fmaxf(v0, v1);
#pragma unroll
      for (int off = 32; off; off >>= 1) mx = fmaxf(mx, __shfl_xor(mx, off));
      const float e0 = expf(v0 - mx), e1 = expf(v1 - mx);
      float s = e0 + e1;
#pragma unroll
      for (int off = 32; off; off >>= 1) s += __shfl_xor(s, off);
      const float inv = 1.f / s;
      Kr[l] = e0 * inv; Kr[l + 64] = e1 * inv;
    }
    __syncthreads();

    // ---- P10: r = wr_t @ M (320 lanes = 80 groups x 4-way n-split) ;
    //      P11: wu update (lanes 320-511, strided) ----
    if (tid < 320) {
      const int g = tid >> 2, ns = tid & 3;   // g = i*40 + q*10 + d4
      const int i = g / 40, rem = g - i * 40;
      const int q = rem / 10, d4 = rem - q * 10;
      const float* Kr = Kp + (i << 9) + q * NN;
      const float* Mb = &M_s[i][4 * d4];
      float4 acc = make_float4(0.f, 0.f, 0.f, 0.f);
#pragma unroll
      for (int j = 0; j < 32; ++j) {
        const int n = ns + 4 * j;
        const float kw = Kr[n];
        const float4 mv = *(const float4*)&Mb[n * MST];
        acc.x += kw * mv.x; acc.y += kw * mv.y;
        acc.z += kw * mv.z; acc.w += kw * mv.w;
      }
#pragma unroll
      for (int off = 2; off; off >>= 1) {
        acc.x += __shfl_xor(acc.x, off);
        acc.y += __shfl_xor(acc.y, off);
        acc.z += __shfl_xor(acc.z, off);
        acc.w += __shfl_xor(acc.w, off);
      }
      if (ns == 0) {
        const int dbase = (q * DD + 4 * d4) * NBAT + i;
        r2[dbase]            = acc.x;
        r2[dbase + NBAT]     = acc.y;
        r2[dbase + 2 * NBAT] = acc.z;
        r2[dbase + 3 * NBAT] = acc.w;
      }
    } else {
      for (int e = tid - 320; e < NBAT * NN; e += 192) {
        const int i = e >> 7, n = e & (NN - 1);
        float s = 0.95f * wu_s[i][n];
#pragma unroll
        for (int q = 0; q < RR; ++q)
          s += Kp[(i << 9) + q * NN + n] + ww_s[i][q * NN + n];
        wu_s[i][n] = s;
      }
    }
    __syncthreads();

    // ---- P12: out (waves 0-1) ; wr <- wr_t (waves 4-7) ----
    if (tid < NBAT * 64) {
      const int i = tid >> 6, l = tid & 63;
      const size_t ob = ((size_t)(b0 + i) * TB + t) * NCLS;
#pragma unroll
      for (int j = 0; j < NCLS; ++j) {
        float p = 0.f;
        for (int k = l; k < HH; k += 64)      p += h2[k * NBAT + i] * Who_s[j * HH + k];
        for (int m = l; m < RR * DD; m += 64) p += r2[m * NBAT + i] * Wro_s[j * RR * DD + m];
#pragma unroll
        for (int off = 32; off; off >>= 1) p += __shfl_xor(p, off);
        if (l == 0) out[ob + j] = p + bo_s[j];
      }
    } else if (tid >= 256) {
      for (int f = tid - 256; f < NBAT * RR * NN; f += 256) (&wr_s[0][0])[f] = Kp[f];
    }
    __syncthreads();
  }
}

// ---------------------------------------------------------------------------
extern "C" void kernel_launch(void* const* d_in, const int* in_sizes, int n_in,
                              void* d_out, int out_size, void* d_ws, size_t ws_size,
                              hipStream_t stream) {
  const float* x    = (const float*)d_in[0];
  const float* Wkey = (const float*)d_in[1];
  const float* bkey = (const float*)d_in[2];
  const float* Wadd = (const float*)d_in[3];
  const float* badd = (const float*)d_in[4];
  const float* Wsig = (const float*)d_in[5];
  const float* bsig = (const float*)d_in[6];
  const float* Who  = (const float*)d_in[7];
  const float* bho  = (const float*)d_in[8];
  const float* Wro  = (const float*)d_in[9];
  const float* bro  = (const float*)d_in[10];
  const float* Wrh  = (const float*)d_in[11];
  const float* brh  = (const float*)d_in[12];
  const float* Wih  = (const float*)d_in[13];
  const float* bih  = (const float*)d_in[14];
  const float* Whh  = (const float*)d_in[15];
  const float* bhh  = (const float*)d_in[16];

  float* ws   = (float*)d_ws;
  float* G    = ws;                       // 25600*800
  float* WhhT = G + (size_t)25600 * 800;  // 160,000
  float* WrhT = WhhT + 160000;            // 32,000
  float* WkaT = WrhT + 32000;             // 64,800
  float* bka  = WkaT + 64800;             // 324

  prep_kernel<<<(160000 + 255) / 256, 256, 0, stream>>>(
      Whh, Wrh, Wkey, Wadd, Wsig, bkey, badd, bsig, WhhT, WrhT, WkaT, bka);

  dim3 gA(G4H / GN, 25600 / GM);   // (10, 200)
  gemm_in2_kernel<<<gA, 256, 0, stream>>>(x, Wih, bih, bhh, G);

  mann_kernel<<<NBLK, 512, 0, stream>>>(G, WhhT, WrhT, WkaT, bka, brh,
                                        Who, bho, Wro, bro, (float*)d_out);
}

// Round 11
// 2795.393 us; speedup vs baseline: 1.2339x; 1.0123x over previous
//
// MANN/NTM forward — R20: R19 + bf16 k-pair-packed recurrence weights.
// GEMV lane geometry pinned (R11-R16) — but those all moved ADDRESS->LANE
// mapping. Here: identical lane count, identical 16B loads, identical k-major
// rotated sweep; one load now covers 4 j x 2 k (bf16 pairs) so each lane's
// serial load chain HALVES (P2 200->100, P4 100->50, P1 80->40). Chains are
// load-latency-bound (VALU 10.5%) -> expect ~30-45% off GEMV phase time.
// Weights RNE-rounded to bf16 (~0.2%/matvec noise; threshold margin 4x).
#include <hip/hip_runtime.h>
#include <math.h>

#define TB   100
#define BB   256
#define INF_ 784
#define HH   200
#define RR   4
#define NN   128
#define DD   40
#define NCLS 5
#define G4H  800   // 4*H
#define KAW  324   // 160 key + 160 add + 1 sigma + 3 pad
#define MST  44    // padded M row stride
#define NBAT 2     // batches per block
#define NBLK (BB / NBAT)

typedef __attribute__((ext_vector_type(8))) short bf16x8;
typedef __attribute__((ext_vector_type(4))) float f32x4;

__device__ __forceinline__ float sigmoidf_(float x) { return 1.0f / (1.0f + expf(-x)); }

__device__ __forceinline__ void splitbf_(float v, unsigned short &hi, unsigned short &lo) {
  const unsigned b = __float_as_uint(v);
  hi = (unsigned short)(b >> 16);
  const float hf = __uint_as_float(b & 0xFFFF0000u);
  lo = (unsigned short)(__float_as_uint(v - hf) >> 16);
}

__device__ __forceinline__ unsigned short bf16rne_(float v) {
  const unsigned u = __float_as_uint(v);
  return (unsigned short)((u + 0x7FFFu + ((u >> 16) & 1u)) >> 16);
}

#define ADV(c, CC) { ++(c); if ((c) == (CC)) (c) = 0; }

// 4-slot rotating software pipeline (3 chunks of loads in flight ahead of FMA).
#define PIPE4(CC, OFS, LOADM, FMAM)                                     \
  {                                                                     \
    int chL = (OFS), chF = (OFS);                                       \
    LOADM(w0, chL); ADV(chL, CC); LOADM(w1, chL); ADV(chL, CC);         \
    LOADM(w2, chL); ADV(chL, CC);                                       \
    _Pragma("unroll 1")                                                 \
    for (int g = 0; g < ((CC) - 3) / 4; ++g) {                          \
      LOADM(w3, chL); ADV(chL, CC); FMAM(w0, chF); ADV(chF, CC);        \
      LOADM(w0, chL); ADV(chL, CC); FMAM(w1, chF); ADV(chF, CC);        \
      LOADM(w1, chL); ADV(chL, CC); FMAM(w2, chF); ADV(chF, CC);        \
      LOADM(w2, chL); ADV(chL, CC); FMAM(w3, chF); ADV(chF, CC);        \
    }                                                                   \
    {                                                                   \
      constexpr int REMX = (CC) - 3 - 4 * (((CC) - 3) / 4);             \
      if (REMX >= 1) { LOADM(w3, chL); ADV(chL, CC); }                  \
      FMAM(w0, chF); ADV(chF, CC);                                      \
      if (REMX >= 2) { LOADM(w0, chL); ADV(chL, CC); }                  \
      FMAM(w1, chF); ADV(chF, CC);                                      \
      if (REMX >= 3) { LOADM(w1, chL); ADV(chL, CC); }                  \
      FMAM(w2, chF); ADV(chF, CC);                                      \
      if (REMX >= 1) { FMAM(w3, chF); ADV(chF, CC); }                   \
      if (REMX >= 2) { FMAM(w0, chF); ADV(chF, CC); }                   \
      if (REMX >= 3) { FMAM(w1, chF); ADV(chF, CC); }                   \
    }                                                                   \
  }

// bf16-pair unpack: one u32 = (k-even in low16, k-odd in high16)
#define BFUP(V, WE, WO)                                                  \
  const float WE = __uint_as_float((unsigned)(V) << 16);                 \
  const float WO = __uint_as_float((unsigned)(V) & 0xFFFF0000u);

// ---------------------------------------------------------------------------
// Prep: bf16 k-pair-packed weights.  Layout: idx = (k>>1)*(2*J) + j*2 + (k&1)
// ---------------------------------------------------------------------------
__global__ __launch_bounds__(256) void prep_kernel(
    const float* __restrict__ Whh, const float* __restrict__ Wrh,
    const float* __restrict__ Wkey, const float* __restrict__ Wadd,
    const float* __restrict__ Wsig, const float* __restrict__ bkey,
    const float* __restrict__ badd, const float* __restrict__ bsig,
    unsigned short* __restrict__ WhhP, unsigned short* __restrict__ WrhP,
    unsigned short* __restrict__ WkaP, float* __restrict__ bka)
{
  const int tid = blockIdx.x * 256 + threadIdx.x;
  if (tid < 160000) {            // Whh (800j, 200k) -> packed [k2][800][2]
    const int j = tid / 200, k = tid - j * 200;
    WhhP[(k >> 1) * 1600 + j * 2 + (k & 1)] = bf16rne_(Whh[tid]);
  }
  if (tid < 32000) {             // Wrh (200j, 160m) -> packed [m2][200][2]
    const int j = tid / 160, m = tid - j * 160;
    WrhP[(m >> 1) * 400 + j * 2 + (m & 1)] = bf16rne_(Wrh[tid]);
  }
  if (tid < 200 * KAW) {         // [Wkey|Wadd|Wsig] -> packed [k2][324][2]
    const int k = tid / KAW, j = tid - k * KAW;
    float v = 0.0f;
    if (j < 160)       v = Wkey[j * HH + k];
    else if (j < 320)  v = Wadd[(j - 160) * HH + k];
    else if (j == 320) v = Wsig[k];
    WkaP[(k >> 1) * (2 * KAW) + j * 2 + (k & 1)] = bf16rne_(v);
  }
  if (tid < KAW) {
    float v = 0.0f;
    if (tid < 160)       v = bkey[tid];
    else if (tid < 320)  v = badd[tid - 160];
    else if (tid == 320) v = bsig[0];
    bka[tid] = v;
  }
}

// ---------------------------------------------------------------------------
// gemm_in2: G[m,j] = sum_k x[m,k]*Wih[j,k] + bih[j] + bhh[j]  (MFMA bf16,
// split-precision hi/lo). Tile 128(M) x 80(N), 256 thr = 4 waves, K-step 32.
// ---------------------------------------------------------------------------
#define GM  128
#define GN  80
#define LDK 40   // padded K stride in bf16 elems (80B, 16B-aligned rows)

__global__ __launch_bounds__(256) void gemm_in2_kernel(
    const float* __restrict__ X, const float* __restrict__ Wih,
    const float* __restrict__ bih, const float* __restrict__ bhh,
    float* __restrict__ G)
{
  __shared__ __attribute__((aligned(16))) unsigned short Ahi[GM][LDK];
  __shared__ __attribute__((aligned(16))) unsigned short Alo[GM][LDK];
  __shared__ __attribute__((aligned(16))) unsigned short Bhi[GN][LDK];
  __shared__ __attribute__((aligned(16))) unsigned short Blo[GN][LDK];

  const int tid  = threadIdx.x;
  const int wv   = tid >> 6, lane = tid & 63;
  const int n0   = blockIdx.x * GN;
  const int m0   = blockIdx.y * GM;

  f32x4 acc[2][5];
#pragma unroll
  for (int mt = 0; mt < 2; ++mt)
#pragma unroll
    for (int nt = 0; nt < 5; ++nt) acc[mt][nt] = (f32x4){0.f, 0.f, 0.f, 0.f};

  const int arow = tid >> 1, ak = (tid & 1) * 16;
  const float* Ap = X + (size_t)(m0 + arow) * INF_ + ak;
  const float* Bp = Wih + (size_t)(n0 + arow) * INF_ + ak;  // arow<80 when tid<160

  const int fr = lane & 15, fk = (lane >> 4) * 8;

  for (int kk = 0; kk < 800; kk += 32) {
    // ---- global loads (zero-padded past K=784; 784%16==0 so per-16 guard) ----
    float va[16], vb[16];
    const bool av = (kk + ak) < INF_;
#pragma unroll
    for (int i = 0; i < 16; ++i) va[i] = 0.f;
    if (av) {
      *(float4*)&va[0]  = *(const float4*)(Ap + kk);
      *(float4*)&va[4]  = *(const float4*)(Ap + kk + 4);
      *(float4*)&va[8]  = *(const float4*)(Ap + kk + 8);
      *(float4*)&va[12] = *(const float4*)(Ap + kk + 12);
    }
    if (tid < 160) {
#pragma unroll
      for (int i = 0; i < 16; ++i) vb[i] = 0.f;
      if (av) {
        *(float4*)&vb[0]  = *(const float4*)(Bp + kk);
        *(float4*)&vb[4]  = *(const float4*)(Bp + kk + 4);
        *(float4*)&vb[8]  = *(const float4*)(Bp + kk + 8);
        *(float4*)&vb[12] = *(const float4*)(Bp + kk + 12);
      }
    }
    __syncthreads();   // prior compute done before LDS overwrite
    // ---- convert + store to LDS ----
    {
      unsigned ah[8], al[8];
#pragma unroll
      for (int i = 0; i < 8; ++i) {
        unsigned short h0, l0, h1, l1;
        splitbf_(va[2 * i], h0, l0);
        splitbf_(va[2 * i + 1], h1, l1);
        ah[i] = (unsigned)h0 | ((unsigned)h1 << 16);
        al[i] = (unsigned)l0 | ((unsigned)l1 << 16);
      }
      ((int4*)&Ahi[arow][ak])[0] = make_int4(ah[0], ah[1], ah[2], ah[3]);
      ((int4*)&Ahi[arow][ak + 8])[0] = make_int4(ah[4], ah[5], ah[6], ah[7]);
      ((int4*)&Alo[arow][ak])[0] = make_int4(al[0], al[1], al[2], al[3]);
      ((int4*)&Alo[arow][ak + 8])[0] = make_int4(al[4], al[5], al[6], al[7]);
    }
    if (tid < 160) {
      unsigned bh[8], bl[8];
#pragma unroll
      for (int i = 0; i < 8; ++i) {
        unsigned short h0, l0, h1, l1;
        splitbf_(vb[2 * i], h0, l0);
        splitbf_(vb[2 * i + 1], h1, l1);
        bh[i] = (unsigned)h0 | ((unsigned)h1 << 16);
        bl[i] = (unsigned)l0 | ((unsigned)l1 << 16);
      }
      ((int4*)&Bhi[arow][ak])[0] = make_int4(bh[0], bh[1], bh[2], bh[3]);
      ((int4*)&Bhi[arow][ak + 8])[0] = make_int4(bh[4], bh[5], bh[6], bh[7]);
      ((int4*)&Blo[arow][ak])[0] = make_int4(bl[0], bl[1], bl[2], bl[3]);
      ((int4*)&Blo[arow][ak + 8])[0] = make_int4(bl[4], bl[5], bl[6], bl[7]);
    }
    __syncthreads();
    // ---- MFMA: 2 m-tiles x 5 n-tiles x 3 passes ----
    const bf16x8 a0h = *(const bf16x8*)&Ahi[wv * 32 + fr][fk];
    const bf16x8 a0l = *(const bf16x8*)&Alo[wv * 32 + fr][fk];
    const bf16x8 a1h = *(const bf16x8*)&Ahi[wv * 32 + 16 + fr][fk];
    const bf16x8 a1l = *(const bf16x8*)&Alo[wv * 32 + 16 + fr][fk];
#pragma unroll
    for (int nt = 0; nt < 5; ++nt) {
      const bf16x8 bh = *(const bf16x8*)&Bhi[nt * 16 + fr][fk];
      const bf16x8 bl = *(const bf16x8*)&Blo[nt * 16 + fr][fk];
      acc[0][nt] = __builtin_amdgcn_mfma_f32_16x16x32_bf16(a0h, bh, acc[0][nt], 0, 0, 0);
      acc[1][nt] = __builtin_amdgcn_mfma_f32_16x16x32_bf16(a1h, bh, acc[1][nt], 0, 0, 0);
      acc[0][nt] = __builtin_amdgcn_mfma_f32_16x16x32_bf16(a0l, bh, acc[0][nt], 0, 0, 0);
      acc[1][nt] = __builtin_amdgcn_mfma_f32_16x16x32_bf16(a1l, bh, acc[1][nt], 0, 0, 0);
      acc[0][nt] = __builtin_amdgcn_mfma_f32_16x16x32_bf16(a0h, bl, acc[0][nt], 0, 0, 0);
      acc[1][nt] = __builtin_amdgcn_mfma_f32_16x16x32_bf16(a1h, bl, acc[1][nt], 0, 0, 0);
    }
  }

  // ---- epilogue: D col = lane&15, row = (lane>>4)*4 + reg ----
#pragma unroll
  for (int nt = 0; nt < 5; ++nt) {
    const int en = n0 + nt * 16 + fr;
    const float bs = bih[en] + bhh[en];
#pragma unroll
    for (int mt = 0; mt < 2; ++mt) {
      const int emb = m0 + wv * 32 + mt * 16 + (lane >> 4) * 4;
#pragma unroll
      for (int r = 0; r < 4; ++r)
        G[(size_t)(emb + r) * G4H + en] = acc[mt][nt][r] + bs;
    }
  }
}

// ---------------------------------------------------------------------------
// Recurrence: one block (512 thr) per 2 batch elements; 128 blocks.
// Weight streams: bf16 k-pair packed, same lane geometry/sweep as R9.
// ---------------------------------------------------------------------------
__global__ __launch_bounds__(512, 2) void mann_kernel(
    const float* __restrict__ G, const unsigned short* __restrict__ WhhP,
    const unsigned short* __restrict__ WrhP, const unsigned short* __restrict__ WkaP,
    const float* __restrict__ bka, const float* __restrict__ brh,
    const float* __restrict__ Who, const float* __restrict__ bho,
    const float* __restrict__ Wro, const float* __restrict__ bro,
    float* __restrict__ out)
{
  __shared__ __attribute__((aligned(16))) float M_s[NBAT][NN * MST];
  __shared__ __attribute__((aligned(16))) float h2[HH * NBAT];   // [k*2+i]
  __shared__ __attribute__((aligned(16))) float c2[HH * NBAT];
  __shared__ __attribute__((aligned(16))) float r2[RR * DD * NBAT];
  __shared__ __attribute__((aligned(16))) float brh_s[HH];
  __shared__ float wr_s[NBAT][RR * NN];
  __shared__ float ww_s[NBAT][RR * NN];
  __shared__ float wu_s[NBAT][NN];
  __shared__ float Mn2_s[NBAT][NN];
  __shared__ float kn2_s[NBAT][RR];
  __shared__ __attribute__((aligned(16))) float gates_s[NBAT][G4H];
  __shared__ __attribute__((aligned(16))) float ka_s[NBAT][KAW];
  __shared__ __attribute__((aligned(16))) float bka_s[KAW];
  __shared__ __attribute__((aligned(16))) float Gbuf_s[NBAT][G4H];
  __shared__ float Who_s[NCLS * HH], Wro_s[NCLS * RR * DD], bo_s[NCLS];
  __shared__ int   lu_s[NBAT][RR];

  // Aliases into the gates region (temporally disjoint):
  float*  Kp   = &gates_s[0][0];          // [2][512] wr_t (P8..P12)
  float4* pkA4 = (float4*)&gates_s[0][0]; // P1 partials batch0 (50 float4)
  float4* pkB4 = pkA4 + 50;               // P1 partials batch1
  float4* pka4 = (float4*)&gates_s[0][0]; // P4 partials: [0..80]=b0, [81..161]=b1

  const int tid = threadIdx.x;
  const int b0  = blockIdx.x * NBAT;

  // ---- init ----
  for (int e = tid; e < NBAT * NN * MST; e += 512) (&M_s[0][0])[e] = 0.f;
  for (int e = tid; e < NBAT * RR * NN; e += 512) (&wr_s[0][0])[e] = 0.f;
  if (tid < NBAT * NN) (&wu_s[0][0])[tid] = 0.f;
  for (int e = tid; e < HH * NBAT; e += 512) { h2[e] = 0.f; c2[e] = 0.f; }
  if (tid < RR * DD * NBAT) r2[tid] = 0.f;
  if (tid < HH) brh_s[tid] = brh[tid];
  if (tid < KAW) bka_s[tid] = bka[tid];
  for (int e = tid; e < NCLS * HH; e += 512) Who_s[e] = Who[e];
  for (int e = tid; e < NCLS * RR * DD; e += 512) Wro_s[e] = Wro[e];
  if (tid < NCLS) bo_s[tid] = bho[tid] + bro[tid];
  if (tid < NBAT * 200) {
    const int i = tid / 200, o = tid - i * 200;
    ((float4*)&Gbuf_s[i][0])[o] =
        ((const float4*)(G + ((size_t)(b0 + i) * TB) * G4H))[o];
  }
  __syncthreads();

  const int ofs1 = (int)((blockIdx.x * 3u) % 8u);   // P1: 8 chunks
  const int ofs2 = (int)((blockIdx.x * 7u) % 20u);  // P2: 20 chunks
  const int ofs4 = (int)((blockIdx.x * 3u) % 10u);  // P4: 10 chunks

#pragma clang loop unroll(disable)
  for (int t = 0; t < TB; ++t) {
    float4 a0v = make_float4(0.f, 0.f, 0.f, 0.f);
    float4 a1v = make_float4(0.f, 0.f, 0.f, 0.f);

    // ---- P1: h += r @ Wrh^T + brh (100 lanes: 50 j4 x 2 k-halves, packed) ----
    if (tid < 100) {
      const int kh = tid / 50, j4 = tid - kh * 50;
      const int k2beg = kh * 40;
      const int4* __restrict__ Wr4 = (const int4*)WrhP + (size_t)k2beg * 50 + j4;
      int4 w0[5], w1[5], w2[5], w3[5];
#define P1_LOAD(B, CH) { const int mm = (CH) * 5; _Pragma("unroll") \
      for (int u = 0; u < 5; ++u) B[u] = Wr4[(mm + u) * 50]; }
#define P1_FMA(B, CH) { const int kc = k2beg + (CH) * 5; _Pragma("unroll") \
      for (int u = 0; u < 5; ++u) { \
        const float4 rk = *(const float4*)&r2[(kc + u) * 4]; \
        BFUP(B[u].x, we0, wo0) BFUP(B[u].y, we1, wo1) \
        BFUP(B[u].z, we2, wo2) BFUP(B[u].w, we3, wo3) \
        a0v.x += rk.x * we0 + rk.z * wo0;  a1v.x += rk.y * we0 + rk.w * wo0; \
        a0v.y += rk.x * we1 + rk.z * wo1;  a1v.y += rk.y * we1 + rk.w * wo1; \
        a0v.z += rk.x * we2 + rk.z * wo2;  a1v.z += rk.y * we2 + rk.w * wo2; \
        a0v.w += rk.x * we3 + rk.z * wo3;  a1v.w += rk.y * we3 + rk.w * wo3; } }
      PIPE4(8, ofs1, P1_LOAD, P1_FMA)
      if (kh) { pkA4[j4] = a0v; pkB4[j4] = a1v; }
    }
    __syncthreads();
    if (tid < 50) {
      const int j4 = tid;
      const float4 pA = pkA4[j4], pB = pkB4[j4];
      const float4 brv = ((const float4*)brh_s)[j4];
      float4 hv0 = *(const float4*)&h2[8 * j4];
      float4 hv1 = *(const float4*)&h2[8 * j4 + 4];
      hv0.x += brv.x + a0v.x + pA.x;  hv0.y += brv.x + a1v.x + pB.x;
      hv0.z += brv.y + a0v.y + pA.y;  hv0.w += brv.y + a1v.y + pB.y;
      hv1.x += brv.z + a0v.z + pA.z;  hv1.y += brv.z + a1v.z + pB.z;
      hv1.z += brv.w + a0v.w + pA.w;  hv1.w += brv.w + a1v.w + pB.w;
      *(float4*)&h2[8 * j4]     = hv0;
      *(float4*)&h2[8 * j4 + 4] = hv1;
    }
    __syncthreads();

    // ---- P2: gates = Gbuf + h @ Whh^T (200 lanes, packed, full k=200) ----
    if (tid < 200) {
      const int4* __restrict__ Wh4 = (const int4*)WhhP + tid;
      float4 g0 = *(const float4*)&Gbuf_s[0][4 * tid];
      float4 g1 = *(const float4*)&Gbuf_s[1][4 * tid];
      int4 w0[5], w1[5], w2[5], w3[5];
#define P2_LOAD(B, CH) { const int kk = (CH) * 5; _Pragma("unroll") \
      for (int u = 0; u < 5; ++u) B[u] = Wh4[(kk + u) * 200]; }
#define P2_FMA(B, CH) { const int kc = (CH) * 5; _Pragma("unroll") \
      for (int u = 0; u < 5; ++u) { \
        const float4 hk = *(const float4*)&h2[(kc + u) * 4]; \
        BFUP(B[u].x, we0, wo0) BFUP(B[u].y, we1, wo1) \
        BFUP(B[u].z, we2, wo2) BFUP(B[u].w, we3, wo3) \
        g0.x += hk.x * we0 + hk.z * wo0;  g1.x += hk.y * we0 + hk.w * wo0; \
        g0.y += hk.x * we1 + hk.z * wo1;  g1.y += hk.y * we1 + hk.w * wo1; \
        g0.z += hk.x * we2 + hk.z * wo2;  g1.z += hk.y * we2 + hk.w * wo2; \
        g0.w += hk.x * we3 + hk.z * wo3;  g1.w += hk.y * we3 + hk.w * wo3; } }
      PIPE4(20, ofs2, P2_LOAD, P2_FMA)
      *(float4*)&gates_s[0][4 * tid] = g0;
      *(float4*)&gates_s[1][4 * tid] = g1;
    }
    __syncthreads();

    // ---- P3: LSTM pointwise (400 items) ----
    if (tid < NBAT * HH) {
      const int i = tid / HH, k = tid - i * HH;
      const float ig = sigmoidf_(gates_s[i][k]);
      const float fg = sigmoidf_(gates_s[i][HH + k]);
      const float gg = tanhf(gates_s[i][2 * HH + k]);
      const float og = sigmoidf_(gates_s[i][3 * HH + k]);
      const float cn = fg * c2[k * NBAT + i] + ig * gg;
      c2[k * NBAT + i] = cn;
      h2[k * NBAT + i] = og * tanhf(cn);
    }
    __syncthreads();

    // ---- P4: [key|add|sigma] = bka + h @ Wka^T (162 lanes, packed) ;
    //      lanes>=384 prefetch G(t+1) ----
    float4 kav0 = make_float4(0.f, 0.f, 0.f, 0.f);
    float4 kav1 = make_float4(0.f, 0.f, 0.f, 0.f);
    if (tid < 162) {
      const int kh = tid / 81, j4 = tid - kh * 81;
      const int k2beg = kh * 50;
      const int4* __restrict__ Wk4 = (const int4*)WkaP + (size_t)k2beg * 81 + j4;
      int4 w0[5], w1[5], w2[5], w3[5];
#define P4_LOAD(B, CH) { const int kk = (CH) * 5; _Pragma("unroll") \
      for (int u = 0; u < 5; ++u) B[u] = Wk4[(kk + u) * 81]; }
#define P4_FMA(B, CH) { const int kc = k2beg + (CH) * 5; _Pragma("unroll") \
      for (int u = 0; u < 5; ++u) { \
        const float4 hk = *(const float4*)&h2[(kc + u) * 4]; \
        BFUP(B[u].x, we0, wo0) BFUP(B[u].y, we1, wo1) \
        BFUP(B[u].z, we2, wo2) BFUP(B[u].w, we3, wo3) \
        kav0.x += hk.x * we0 + hk.z * wo0;  kav1.x += hk.y * we0 + hk.w * wo0; \
        kav0.y += hk.x * we1 + hk.z * wo1;  kav1.y += hk.y * we1 + hk.w * wo1; \
        kav0.z += hk.x * we2 + hk.z * wo2;  kav1.z += hk.y * we2 + hk.w * wo2; \
        kav0.w += hk.x * we3 + hk.z * wo3;  kav1.w += hk.y * we3 + hk.w * wo3; } }
      PIPE4(10, ofs4, P4_LOAD, P4_FMA)
      if (kh) { pka4[j4] = kav0; pka4[81 + j4] = kav1; }
    } else if (tid >= 384 && t + 1 < TB) {
      for (int idx = tid - 384; idx < NBAT * 200; idx += 128) {
        const int i = idx / 200, o = idx - i * 200;
        ((float4*)&Gbuf_s[i][0])[o] =
            ((const float4*)(G + ((size_t)(b0 + i) * TB + t + 1) * G4H))[o];
      }
    }
    __syncthreads();
    if (tid < 81) {
      const float4 bbv = ((const float4*)bka_s)[tid];
      const float4 p0 = pka4[tid], p1 = pka4[81 + tid];
      float4 v0, v1;
      v0.x = kav0.x + p0.x + bbv.x; v0.y = kav0.y + p0.y + bbv.y;
      v0.z = kav0.z + p0.z + bbv.z; v0.w = kav0.w + p0.w + bbv.w;
      v1.x = kav1.x + p1.x + bbv.x; v1.y = kav1.y + p1.y + bbv.y;
      v1.z = kav1.z + p1.z + bbv.z; v1.w = kav1.w + p1.w + bbv.w;
      *(float4*)&ka_s[0][4 * tid] = v0;
      *(float4*)&ka_s[1][4 * tid] = v1;
    }
    __syncthreads();

    // ---- P5: least-used select (waves 0-1, one per batch) + key norms ----
    if (tid < NBAT * 64) {
      const int i = tid >> 6, l = tid & 63;
      unsigned u0v = __float_as_uint(wu_s[i][l]);
      unsigned u1v = __float_as_uint(wu_s[i][l + 64]);
      if (u0v == 0x80000000u) u0v = 0u;
      if (u1v == 0x80000000u) u1v = 0u;
      u0v = (u0v & 0x80000000u) ? ~u0v : (u0v | 0x80000000u);
      u1v = (u1v & 0x80000000u) ? ~u1v : (u1v | 0x80000000u);
      unsigned long long k0 = ((unsigned long long)u0v << 32) | (unsigned)l;
      unsigned long long k1 = ((unsigned long long)u1v << 32) | (unsigned)(l + 64);
#pragma unroll
      for (int rsel = 0; rsel < RR; ++rsel) {
        unsigned long long mn = (k0 < k1) ? k0 : k1;
#pragma unroll
        for (int off = 32; off; off >>= 1) {
          const unsigned long long o = __shfl_xor(mn, off);
          if (o < mn) mn = o;
        }
        const int idx = (int)(mn & 0xFFFFFFFFull);
        if (l == 0) lu_s[i][rsel] = idx;
        if (idx == l)      k0 = ~0ull;
        if (idx == l + 64) k1 = ~0ull;
      }
    } else if (tid < NBAT * 64 + NBAT * RR) {
      const int e = tid - NBAT * 64;
      const int i = e >> 2, q = e & 3;
      float s = 0.f;
#pragma unroll
      for (int d4 = 0; d4 < 10; ++d4) {
        const float4 v = *(const float4*)&ka_s[i][q * DD + 4 * d4];
        s += v.x * v.x + v.y * v.y + v.z * v.z + v.w * v.w;
      }
      kn2_s[i][q] = s;
    }
    __syncthreads();

    // ---- P7 (P6 fused): ww inline; M = M*wlu + ww^T @ add ; row-norm ----
    if (tid < NBAT * NN) {
      const int i = tid >> 7, n = tid & (NN - 1);
      const int l0 = lu_s[i][0], l1 = lu_s[i][1], l2 = lu_s[i][2], l3 = lu_s[i][3];
      const float wlu = (n == l0 || n == l1 || n == l2 || n == l3) ? 1.f : 0.f;
      const float sg = ka_s[i][320];
      const float oms = (1.f - sg) * wlu;
      const float wwv0 = sg * wr_s[i][n]          + oms;
      const float wwv1 = sg * wr_s[i][NN + n]     + oms;
      const float wwv2 = sg * wr_s[i][2 * NN + n] + oms;
      const float wwv3 = sg * wr_s[i][3 * NN + n] + oms;
      ww_s[i][n]          = wwv0;
      ww_s[i][NN + n]     = wwv1;
      ww_s[i][2 * NN + n] = wwv2;
      ww_s[i][3 * NN + n] = wwv3;
      float* Mr = &M_s[i][n * MST];
      const float* Ad = &ka_s[i][160];
      float mn2 = 0.f;
#pragma unroll
      for (int d4 = 0; d4 < 10; ++d4) {
        float4 m = *(const float4*)&Mr[4 * d4];
        m.x *= wlu; m.y *= wlu; m.z *= wlu; m.w *= wlu;
        const float4 av0 = *(const float4*)&Ad[0 * DD + 4 * d4];
        const float4 av1 = *(const float4*)&Ad[1 * DD + 4 * d4];
        const float4 av2 = *(const float4*)&Ad[2 * DD + 4 * d4];
        const float4 av3 = *(const float4*)&Ad[3 * DD + 4 * d4];
        m.x += wwv0 * av0.x + wwv1 * av1.x + wwv2 * av2.x + wwv3 * av3.x;
        m.y += wwv0 * av0.y + wwv1 * av1.y + wwv2 * av2.y + wwv3 * av3.y;
        m.z += wwv0 * av0.z + wwv1 * av1.z + wwv2 * av2.z + wwv3 * av3.z;
        m.w += wwv0 * av0.w + wwv1 * av1.w + wwv2 * av2.w + wwv3 * av3.w;
        *(float4*)&Mr[4 * d4] = m;
        mn2 += m.x * m.x + m.y * m.y + m.z * m.z + m.w * m.w;
      }
      Mn2_s[i][n] = mn2;
    }
    __syncthreads();

    // ---- P8: K = cosine(key, M): 512 lanes, each reads one M row, 2 keys ----
    {
      const int i = tid >> 8, qq = (tid >> 7) & 1, n = tid & (NN - 1);
      const float* Mr = &M_s[i][n * MST];
      const float* Ky0 = &ka_s[i][qq * DD];
      const float* Ky1 = &ka_s[i][(qq + 2) * DD];
      float s0 = 0.f, s1 = 0.f;
#pragma unroll
      for (int d4 = 0; d4 < 10; ++d4) {
        const float4 mv = *(const float4*)&Mr[4 * d4];
        const float4 k0v = *(const float4*)&Ky0[4 * d4];
        const float4 k1v = *(const float4*)&Ky1[4 * d4];
        s0 += k0v.x * mv.x + k0v.y * mv.y + k0v.z * mv.z + k0v.w * mv.w;
        s1 += k1v.x * mv.x + k1v.y * mv.y + k1v.z * mv.z + k1v.w * mv.w;
      }
      const float mn2 = Mn2_s[i][n];
      Kp[(i << 9) + qq * NN + n]       = s0 / sqrtf(kn2_s[i][qq] * mn2 + 1e-6f);
      Kp[(i << 9) + (qq + 2) * NN + n] = s1 / sqrtf(kn2_s[i][qq + 2] * mn2 + 1e-6f);
    }
    __syncthreads();

    // ---- P9: softmax over N (8 rows, one per wave) ----
    {
      const int w = tid >> 6, l = tid & 63;
      float* Kr = Kp + ((w >> 2) << 9) + (w & 3) * NN;
      const float v0 = Kr[l], v1 = Kr[l + 64];
      float mx = fmaxf(v0, v1);
#pragma unroll
      for (int off = 32; off; off >>= 1) mx = fmaxf(mx, __shfl_xor(mx, off));
      const float e0 = expf(v0 - mx), e1 = expf(v1 - mx);
      float s = e0 + e1;
#pragma unroll
      for (int off = 32; off; off >>= 1) s += __shfl_xor(s, off);
      const float inv = 1.f / s;
      Kr[l] = e0 * inv; Kr[l + 64] = e1 * inv;
    }
    __syncthreads();

    // ---- P10: r = wr_t @ M (320 lanes = 80 groups x 4-way n-split) ;
    //      P11: wu update (lanes 320-511, strided) ----
    if (tid < 320) {
      const int g = tid >> 2, ns = tid & 3;   // g = i*40 + q*10 + d4
      const int i = g / 40, rem = g - i * 40;
      const int q = rem / 10, d4 = rem - q * 10;
      const float* Kr = Kp + (i << 9) + q * NN;
      const float* Mb = &M_s[i][4 * d4];
      float4 acc = make_float4(0.f, 0.f, 0.f, 0.f);
#pragma unroll
      for (int j = 0; j < 32; ++j) {
        const int n = ns + 4 * j;
        const float kw = Kr[n];
        const float4 mv = *(const float4*)&Mb[n * MST];
        acc.x += kw * mv.x; acc.y += kw * mv.y;
        acc.z += kw * mv.z; acc.w += kw * mv.w;
      }
#pragma unroll
      for (int off = 2; off; off >>= 1) {
        acc.x += __shfl_xor(acc.x, off);
        acc.y += __shfl_xor(acc.y, off);
        acc.z += __shfl_xor(acc.z, off);
        acc.w += __shfl_xor(acc.w, off);
      }
      if (ns == 0) {
        const int dbase = (q * DD + 4 * d4) * NBAT + i;
        r2[dbase]            = acc.x;
        r2[dbase + NBAT]     = acc.y;
        r2[dbase + 2 * NBAT] = acc.z;
        r2[dbase + 3 * NBAT] = acc.w;
      }
    } else {
      for (int e = tid - 320; e < NBAT * NN; e += 192) {
        const int i = e >> 7, n = e & (NN - 1);
        float s = 0.95f * wu_s[i][n];
#pragma unroll
        for (int q = 0; q < RR; ++q)
          s += Kp[(i << 9) + q * NN + n] + ww_s[i][q * NN + n];
        wu_s[i][n] = s;
      }
    }
    __syncthreads();

    // ---- P12: out (waves 0-1) ; wr <- wr_t (waves 4-7) ----
    if (tid < NBAT * 64) {
      const int i = tid >> 6, l = tid & 63;
      const size_t ob = ((size_t)(b0 + i) * TB + t) * NCLS;
#pragma unroll
      for (int j = 0; j < NCLS; ++j) {
        float p = 0.f;
        for (int k = l; k < HH; k += 64)      p += h2[k * NBAT + i] * Who_s[j * HH + k];
        for (int m = l; m < RR * DD; m += 64) p += r2[m * NBAT + i] * Wro_s[j * RR * DD + m];
#pragma unroll
        for (int off = 32; off; off >>= 1) p += __shfl_xor(p, off);
        if (l == 0) out[ob + j] = p + bo_s[j];
      }
    } else if (tid >= 256) {
      for (int f = tid - 256; f < NBAT * RR * NN; f += 256) (&wr_s[0][0])[f] = Kp[f];
    }
    __syncthreads();
  }
}

// ---------------------------------------------------------------------------
extern "C" void kernel_launch(void* const* d_in, const int* in_sizes, int n_in,
                              void* d_out, int out_size, void* d_ws, size_t ws_size,
                              hipStream_t stream) {
  const float* x    = (const float*)d_in[0];
  const float* Wkey = (const float*)d_in[1];
  const float* bkey = (const float*)d_in[2];
  const float* Wadd = (const float*)d_in[3];
  const float* badd = (const float*)d_in[4];
  const float* Wsig = (const float*)d_in[5];
  const float* bsig = (const float*)d_in[6];
  const float* Who  = (const float*)d_in[7];
  const float* bho  = (const float*)d_in[8];
  const float* Wro  = (const float*)d_in[9];
  const float* bro  = (const float*)d_in[10];
  const float* Wrh  = (const float*)d_in[11];
  const float* brh  = (const float*)d_in[12];
  const float* Wih  = (const float*)d_in[13];
  const float* bih  = (const float*)d_in[14];
  const float* Whh  = (const float*)d_in[15];
  const float* bhh  = (const float*)d_in[16];

  float* ws = (float*)d_ws;
  float* G  = ws;                                    // 25600*800 floats
  unsigned short* WhhP = (unsigned short*)(G + (size_t)25600 * 800); // 160,000 us
  unsigned short* WrhP = WhhP + 160000;              // 32,000 us
  unsigned short* WkaP = WrhP + 32000;               // 64,800 us
  float* bka = G + (size_t)25600 * 800 + 128400;     // after 256,800 ushorts

  prep_kernel<<<(160000 + 255) / 256, 256, 0, stream>>>(
      Whh, Wrh, Wkey, Wadd, Wsig, bkey, badd, bsig, WhhP, WrhP, WkaP, bka);

  dim3 gA(G4H / GN, 25600 / GM);   // (10, 200)
  gemm_in2_kernel<<<gA, 256, 0, stream>>>(x, Wih, bih, bhh, G);

  mann_kernel<<<NBLK, 512, 0, stream>>>(G, WhhP, WrhP, WkaP, bka, brh,
                                        Who, bho, Wro, bro, (float*)d_out);
}

// Round 12
// 2184.730 us; speedup vs baseline: 1.5788x; 1.2795x over previous
//
// MANN/NTM forward — R21: NBAT=1, 256 blocks, weight-stream geometry
// BIT-IDENTICAL to R20 (same int4 lane->address map, full-k rotated sweep,
// same chunk counts). Audit of R11-R16: every FETCH explosion coincided with
// a changed lane->address map; "256 blocks" was only ever tested confounded
// with k-split (R12). This isolates block count as the variable. If FETCH
// stays ~flat, all 256 CUs work and mann ~halves; if it explodes, revert R20.
#include <hip/hip_runtime.h>
#include <math.h>

#define TB   100
#define BB   256
#define INF_ 784
#define HH   200
#define RR   4
#define NN   128
#define DD   40
#define NCLS 5
#define G4H  800   // 4*H
#define KAW  324   // 160 key + 160 add + 1 sigma + 3 pad
#define MST  44    // padded M row stride

typedef __attribute__((ext_vector_type(8))) short bf16x8;
typedef __attribute__((ext_vector_type(4))) float f32x4;

__device__ __forceinline__ float sigmoidf_(float x) { return 1.0f / (1.0f + expf(-x)); }

__device__ __forceinline__ void splitbf_(float v, unsigned short &hi, unsigned short &lo) {
  const unsigned b = __float_as_uint(v);
  hi = (unsigned short)(b >> 16);
  const float hf = __uint_as_float(b & 0xFFFF0000u);
  lo = (unsigned short)(__float_as_uint(v - hf) >> 16);
}

__device__ __forceinline__ unsigned short bf16rne_(float v) {
  const unsigned u = __float_as_uint(v);
  return (unsigned short)((u + 0x7FFFu + ((u >> 16) & 1u)) >> 16);
}

#define ADV(c, CC) { ++(c); if ((c) == (CC)) (c) = 0; }

// 4-slot rotating software pipeline (3 chunks of loads in flight ahead of FMA).
#define PIPE4(CC, OFS, LOADM, FMAM)                                     \
  {                                                                     \
    int chL = (OFS), chF = (OFS);                                       \
    LOADM(w0, chL); ADV(chL, CC); LOADM(w1, chL); ADV(chL, CC);         \
    LOADM(w2, chL); ADV(chL, CC);                                       \
    _Pragma("unroll 1")                                                 \
    for (int g = 0; g < ((CC) - 3) / 4; ++g) {                          \
      LOADM(w3, chL); ADV(chL, CC); FMAM(w0, chF); ADV(chF, CC);        \
      LOADM(w0, chL); ADV(chL, CC); FMAM(w1, chF); ADV(chF, CC);        \
      LOADM(w1, chL); ADV(chL, CC); FMAM(w2, chF); ADV(chF, CC);        \
      LOADM(w2, chL); ADV(chL, CC); FMAM(w3, chF); ADV(chF, CC);        \
    }                                                                   \
    {                                                                   \
      constexpr int REMX = (CC) - 3 - 4 * (((CC) - 3) / 4);             \
      if (REMX >= 1) { LOADM(w3, chL); ADV(chL, CC); }                  \
      FMAM(w0, chF); ADV(chF, CC);                                      \
      if (REMX >= 2) { LOADM(w0, chL); ADV(chL, CC); }                  \
      FMAM(w1, chF); ADV(chF, CC);                                      \
      if (REMX >= 3) { LOADM(w1, chL); ADV(chL, CC); }                  \
      FMAM(w2, chF); ADV(chF, CC);                                      \
      if (REMX >= 1) { FMAM(w3, chF); ADV(chF, CC); }                   \
      if (REMX >= 2) { FMAM(w0, chF); ADV(chF, CC); }                   \
      if (REMX >= 3) { FMAM(w1, chF); ADV(chF, CC); }                   \
    }                                                                   \
  }

// bf16-pair unpack: one u32 = (k-even in low16, k-odd in high16)
#define BFUP(V, WE, WO)                                                  \
  const float WE = __uint_as_float((unsigned)(V) << 16);                 \
  const float WO = __uint_as_float((unsigned)(V) & 0xFFFF0000u);

// ---------------------------------------------------------------------------
// Prep: bf16 k-pair-packed weights.  Layout: idx = (k>>1)*(2*J) + j*2 + (k&1)
// ---------------------------------------------------------------------------
__global__ __launch_bounds__(256) void prep_kernel(
    const float* __restrict__ Whh, const float* __restrict__ Wrh,
    const float* __restrict__ Wkey, const float* __restrict__ Wadd,
    const float* __restrict__ Wsig, const float* __restrict__ bkey,
    const float* __restrict__ badd, const float* __restrict__ bsig,
    unsigned short* __restrict__ WhhP, unsigned short* __restrict__ WrhP,
    unsigned short* __restrict__ WkaP, float* __restrict__ bka)
{
  const int tid = blockIdx.x * 256 + threadIdx.x;
  if (tid < 160000) {            // Whh (800j, 200k) -> packed [k2][800][2]
    const int j = tid / 200, k = tid - j * 200;
    WhhP[(k >> 1) * 1600 + j * 2 + (k & 1)] = bf16rne_(Whh[tid]);
  }
  if (tid < 32000) {             // Wrh (200j, 160m) -> packed [m2][200][2]
    const int j = tid / 160, m = tid - j * 160;
    WrhP[(m >> 1) * 400 + j * 2 + (m & 1)] = bf16rne_(Wrh[tid]);
  }
  if (tid < 200 * KAW) {         // [Wkey|Wadd|Wsig] -> packed [k2][324][2]
    const int k = tid / KAW, j = tid - k * KAW;
    float v = 0.0f;
    if (j < 160)       v = Wkey[j * HH + k];
    else if (j < 320)  v = Wadd[(j - 160) * HH + k];
    else if (j == 320) v = Wsig[k];
    WkaP[(k >> 1) * (2 * KAW) + j * 2 + (k & 1)] = bf16rne_(v);
  }
  if (tid < KAW) {
    float v = 0.0f;
    if (tid < 160)       v = bkey[tid];
    else if (tid < 320)  v = badd[tid - 160];
    else if (tid == 320) v = bsig[0];
    bka[tid] = v;
  }
}

// ---------------------------------------------------------------------------
// gemm_in2: G[m,j] = sum_k x[m,k]*Wih[j,k] + bih[j] + bhh[j]  (MFMA bf16,
// split-precision hi/lo). Tile 128(M) x 80(N), 256 thr = 4 waves, K-step 32.
// ---------------------------------------------------------------------------
#define GM  128
#define GN  80
#define LDK 40   // padded K stride in bf16 elems (80B, 16B-aligned rows)

__global__ __launch_bounds__(256) void gemm_in2_kernel(
    const float* __restrict__ X, const float* __restrict__ Wih,
    const float* __restrict__ bih, const float* __restrict__ bhh,
    float* __restrict__ G)
{
  __shared__ __attribute__((aligned(16))) unsigned short Ahi[GM][LDK];
  __shared__ __attribute__((aligned(16))) unsigned short Alo[GM][LDK];
  __shared__ __attribute__((aligned(16))) unsigned short Bhi[GN][LDK];
  __shared__ __attribute__((aligned(16))) unsigned short Blo[GN][LDK];

  const int tid  = threadIdx.x;
  const int wv   = tid >> 6, lane = tid & 63;
  const int n0   = blockIdx.x * GN;
  const int m0   = blockIdx.y * GM;

  f32x4 acc[2][5];
#pragma unroll
  for (int mt = 0; mt < 2; ++mt)
#pragma unroll
    for (int nt = 0; nt < 5; ++nt) acc[mt][nt] = (f32x4){0.f, 0.f, 0.f, 0.f};

  const int arow = tid >> 1, ak = (tid & 1) * 16;
  const float* Ap = X + (size_t)(m0 + arow) * INF_ + ak;
  const float* Bp = Wih + (size_t)(n0 + arow) * INF_ + ak;  // arow<80 when tid<160

  const int fr = lane & 15, fk = (lane >> 4) * 8;

  for (int kk = 0; kk < 800; kk += 32) {
    // ---- global loads (zero-padded past K=784; 784%16==0 so per-16 guard) ----
    float va[16], vb[16];
    const bool av = (kk + ak) < INF_;
#pragma unroll
    for (int i = 0; i < 16; ++i) va[i] = 0.f;
    if (av) {
      *(float4*)&va[0]  = *(const float4*)(Ap + kk);
      *(float4*)&va[4]  = *(const float4*)(Ap + kk + 4);
      *(float4*)&va[8]  = *(const float4*)(Ap + kk + 8);
      *(float4*)&va[12] = *(const float4*)(Ap + kk + 12);
    }
    if (tid < 160) {
#pragma unroll
      for (int i = 0; i < 16; ++i) vb[i] = 0.f;
      if (av) {
        *(float4*)&vb[0]  = *(const float4*)(Bp + kk);
        *(float4*)&vb[4]  = *(const float4*)(Bp + kk + 4);
        *(float4*)&vb[8]  = *(const float4*)(Bp + kk + 8);
        *(float4*)&vb[12] = *(const float4*)(Bp + kk + 12);
      }
    }
    __syncthreads();   // prior compute done before LDS overwrite
    // ---- convert + store to LDS ----
    {
      unsigned ah[8], al[8];
#pragma unroll
      for (int i = 0; i < 8; ++i) {
        unsigned short h0, l0, h1, l1;
        splitbf_(va[2 * i], h0, l0);
        splitbf_(va[2 * i + 1], h1, l1);
        ah[i] = (unsigned)h0 | ((unsigned)h1 << 16);
        al[i] = (unsigned)l0 | ((unsigned)l1 << 16);
      }
      ((int4*)&Ahi[arow][ak])[0] = make_int4(ah[0], ah[1], ah[2], ah[3]);
      ((int4*)&Ahi[arow][ak + 8])[0] = make_int4(ah[4], ah[5], ah[6], ah[7]);
      ((int4*)&Alo[arow][ak])[0] = make_int4(al[0], al[1], al[2], al[3]);
      ((int4*)&Alo[arow][ak + 8])[0] = make_int4(al[4], al[5], al[6], al[7]);
    }
    if (tid < 160) {
      unsigned bh[8], bl[8];
#pragma unroll
      for (int i = 0; i < 8; ++i) {
        unsigned short h0, l0, h1, l1;
        splitbf_(vb[2 * i], h0, l0);
        splitbf_(vb[2 * i + 1], h1, l1);
        bh[i] = (unsigned)h0 | ((unsigned)h1 << 16);
        bl[i] = (unsigned)l0 | ((unsigned)l1 << 16);
      }
      ((int4*)&Bhi[arow][ak])[0] = make_int4(bh[0], bh[1], bh[2], bh[3]);
      ((int4*)&Bhi[arow][ak + 8])[0] = make_int4(bh[4], bh[5], bh[6], bh[7]);
      ((int4*)&Blo[arow][ak])[0] = make_int4(bl[0], bl[1], bl[2], bl[3]);
      ((int4*)&Blo[arow][ak + 8])[0] = make_int4(bl[4], bl[5], bl[6], bl[7]);
    }
    __syncthreads();
    // ---- MFMA: 2 m-tiles x 5 n-tiles x 3 passes ----
    const bf16x8 a0h = *(const bf16x8*)&Ahi[wv * 32 + fr][fk];
    const bf16x8 a0l = *(const bf16x8*)&Alo[wv * 32 + fr][fk];
    const bf16x8 a1h = *(const bf16x8*)&Ahi[wv * 32 + 16 + fr][fk];
    const bf16x8 a1l = *(const bf16x8*)&Alo[wv * 32 + 16 + fr][fk];
#pragma unroll
    for (int nt = 0; nt < 5; ++nt) {
      const bf16x8 bh = *(const bf16x8*)&Bhi[nt * 16 + fr][fk];
      const bf16x8 bl = *(const bf16x8*)&Blo[nt * 16 + fr][fk];
      acc[0][nt] = __builtin_amdgcn_mfma_f32_16x16x32_bf16(a0h, bh, acc[0][nt], 0, 0, 0);
      acc[1][nt] = __builtin_amdgcn_mfma_f32_16x16x32_bf16(a1h, bh, acc[1][nt], 0, 0, 0);
      acc[0][nt] = __builtin_amdgcn_mfma_f32_16x16x32_bf16(a0l, bh, acc[0][nt], 0, 0, 0);
      acc[1][nt] = __builtin_amdgcn_mfma_f32_16x16x32_bf16(a1l, bh, acc[1][nt], 0, 0, 0);
      acc[0][nt] = __builtin_amdgcn_mfma_f32_16x16x32_bf16(a0h, bl, acc[0][nt], 0, 0, 0);
      acc[1][nt] = __builtin_amdgcn_mfma_f32_16x16x32_bf16(a1h, bl, acc[1][nt], 0, 0, 0);
    }
  }

  // ---- epilogue: D col = lane&15, row = (lane>>4)*4 + reg ----
#pragma unroll
  for (int nt = 0; nt < 5; ++nt) {
    const int en = n0 + nt * 16 + fr;
    const float bs = bih[en] + bhh[en];
#pragma unroll
    for (int mt = 0; mt < 2; ++mt) {
      const int emb = m0 + wv * 32 + mt * 16 + (lane >> 4) * 4;
#pragma unroll
      for (int r = 0; r < 4; ++r)
        G[(size_t)(emb + r) * G4H + en] = acc[mt][nt][r] + bs;
    }
  }
}

// ---------------------------------------------------------------------------
// Recurrence: one block (512 thr) per batch element; 256 blocks = all CUs.
// Weight streams bit-identical shape to R20 (int4, full-k rotated sweep).
// ---------------------------------------------------------------------------
__global__ __launch_bounds__(512, 2) void mann_kernel(
    const float* __restrict__ G, const unsigned short* __restrict__ WhhP,
    const unsigned short* __restrict__ WrhP, const unsigned short* __restrict__ WkaP,
    const float* __restrict__ bka, const float* __restrict__ brh,
    const float* __restrict__ Who, const float* __restrict__ bho,
    const float* __restrict__ Wro, const float* __restrict__ bro,
    float* __restrict__ out)
{
  __shared__ __attribute__((aligned(16))) float M_s[NN * MST];
  __shared__ __attribute__((aligned(16))) float h_s[HH];
  __shared__ __attribute__((aligned(16))) float c_s[HH];
  __shared__ __attribute__((aligned(16))) float r_s[RR * DD];
  __shared__ __attribute__((aligned(16))) float brh_s[HH];
  __shared__ float wr_s[RR * NN];
  __shared__ float ww_s[RR * NN];
  __shared__ float wu_s[NN];
  __shared__ float Mn2_s[NN];
  __shared__ float kn2_s[RR];
  __shared__ __attribute__((aligned(16))) float gates_s[G4H];
  __shared__ __attribute__((aligned(16))) float ka_s[KAW];
  __shared__ __attribute__((aligned(16))) float bka_s[KAW];
  __shared__ __attribute__((aligned(16))) float Gbuf_s[G4H];
  __shared__ float Who_s[NCLS * HH], Wro_s[NCLS * RR * DD], bo_s[NCLS];
  __shared__ int   lu_s[RR];

  // Aliases into the gates region (temporally disjoint):
  float*  Kp   = &gates_s[0];          // [4*NN] wr_t (P8..P12)
  float4* pkA4 = (float4*)&gates_s[0]; // P1 partials (50 float4)
  float4* pka4 = (float4*)&gates_s[0]; // P4 partials (81 float4)

  const int tid = threadIdx.x;
  const int b   = blockIdx.x;

  // ---- init ----
  for (int e = tid; e < NN * MST; e += 512) M_s[e] = 0.f;
  if (tid < RR * NN) wr_s[tid] = 0.f;
  if (tid < NN) wu_s[tid] = 0.f;
  if (tid < HH) { h_s[tid] = 0.f; c_s[tid] = 0.f; brh_s[tid] = brh[tid]; }
  if (tid < RR * DD) r_s[tid] = 0.f;
  if (tid < KAW) bka_s[tid] = bka[tid];
  for (int e = tid; e < NCLS * HH; e += 512) Who_s[e] = Who[e];
  for (int e = tid; e < NCLS * RR * DD; e += 512) Wro_s[e] = Wro[e];
  if (tid < NCLS) bo_s[tid] = bho[tid] + bro[tid];
  if (tid < 200)
    ((float4*)Gbuf_s)[tid] = ((const float4*)(G + (size_t)b * TB * G4H))[tid];
  __syncthreads();

  const int ofs1 = (int)((blockIdx.x * 3u) % 8u);   // P1: 8 chunks
  const int ofs2 = (int)((blockIdx.x * 7u) % 20u);  // P2: 20 chunks
  const int ofs4 = (int)((blockIdx.x * 3u) % 10u);  // P4: 10 chunks

#pragma clang loop unroll(disable)
  for (int t = 0; t < TB; ++t) {
    float4 a0v = make_float4(0.f, 0.f, 0.f, 0.f);

    // ---- P1: h += r @ Wrh^T + brh (100 lanes: 50 j4 x 2 k-halves, packed) ----
    if (tid < 100) {
      const int kh = tid / 50, j4 = tid - kh * 50;
      const int k2beg = kh * 40;
      const int4* __restrict__ Wr4 = (const int4*)WrhP + (size_t)k2beg * 50 + j4;
      int4 w0[5], w1[5], w2[5], w3[5];
#define P1_LOAD(B, CH) { const int mm = (CH) * 5; _Pragma("unroll") \
      for (int u = 0; u < 5; ++u) B[u] = Wr4[(mm + u) * 50]; }
#define P1_FMA(B, CH) { const int kc = k2beg + (CH) * 5; _Pragma("unroll") \
      for (int u = 0; u < 5; ++u) { \
        const float2 rk = *(const float2*)&r_s[(kc + u) * 2]; \
        BFUP(B[u].x, we0, wo0) BFUP(B[u].y, we1, wo1) \
        BFUP(B[u].z, we2, wo2) BFUP(B[u].w, we3, wo3) \
        a0v.x += rk.x * we0 + rk.y * wo0; \
        a0v.y += rk.x * we1 + rk.y * wo1; \
        a0v.z += rk.x * we2 + rk.y * wo2; \
        a0v.w += rk.x * we3 + rk.y * wo3; } }
      PIPE4(8, ofs1, P1_LOAD, P1_FMA)
      if (kh) pkA4[j4] = a0v;
    }
    __syncthreads();
    if (tid < 50) {
      const float4 pA = pkA4[tid];
      const float4 brv = ((const float4*)brh_s)[tid];
      float4 hv = *(const float4*)&h_s[4 * tid];
      hv.x += brv.x + a0v.x + pA.x;
      hv.y += brv.y + a0v.y + pA.y;
      hv.z += brv.z + a0v.z + pA.z;
      hv.w += brv.w + a0v.w + pA.w;
      *(float4*)&h_s[4 * tid] = hv;
    }
    __syncthreads();

    // ---- P2: gates = Gbuf + h @ Whh^T (200 lanes, packed, full k=200) ----
    if (tid < 200) {
      const int4* __restrict__ Wh4 = (const int4*)WhhP + tid;
      float4 g0 = *(const float4*)&Gbuf_s[4 * tid];
      int4 w0[5], w1[5], w2[5], w3[5];
#define P2_LOAD(B, CH) { const int kk = (CH) * 5; _Pragma("unroll") \
      for (int u = 0; u < 5; ++u) B[u] = Wh4[(kk + u) * 200]; }
#define P2_FMA(B, CH) { const int kc = (CH) * 5; _Pragma("unroll") \
      for (int u = 0; u < 5; ++u) { \
        const float2 hk = *(const float2*)&h_s[(kc + u) * 2]; \
        BFUP(B[u].x, we0, wo0) BFUP(B[u].y, we1, wo1) \
        BFUP(B[u].z, we2, wo2) BFUP(B[u].w, we3, wo3) \
        g0.x += hk.x * we0 + hk.y * wo0; \
        g0.y += hk.x * we1 + hk.y * wo1; \
        g0.z += hk.x * we2 + hk.y * wo2; \
        g0.w += hk.x * we3 + hk.y * wo3; } }
      PIPE4(20, ofs2, P2_LOAD, P2_FMA)
      *(float4*)&gates_s[4 * tid] = g0;
    }
    __syncthreads();

    // ---- P3: LSTM pointwise (200 lanes) ----
    if (tid < HH) {
      const float ig = sigmoidf_(gates_s[tid]);
      const float fg = sigmoidf_(gates_s[HH + tid]);
      const float gg = tanhf(gates_s[2 * HH + tid]);
      const float og = sigmoidf_(gates_s[3 * HH + tid]);
      const float cn = fg * c_s[tid] + ig * gg;
      c_s[tid] = cn;
      h_s[tid] = og * tanhf(cn);
    }
    __syncthreads();

    // ---- P4: [key|add|sigma] = bka + h @ Wka^T (162 lanes, packed) ;
    //      lanes>=384 prefetch G(t+1) ----
    float4 kav0 = make_float4(0.f, 0.f, 0.f, 0.f);
    if (tid < 162) {
      const int kh = tid / 81, j4 = tid - kh * 81;
      const int k2beg = kh * 50;
      const int4* __restrict__ Wk4 = (const int4*)WkaP + (size_t)k2beg * 81 + j4;
      int4 w0[5], w1[5], w2[5], w3[5];
#define P4_LOAD(B, CH) { const int kk = (CH) * 5; _Pragma("unroll") \
      for (int u = 0; u < 5; ++u) B[u] = Wk4[(kk + u) * 81]; }
#define P4_FMA(B, CH) { const int kc = k2beg + (CH) * 5; _Pragma("unroll") \
      for (int u = 0; u < 5; ++u) { \
        const float2 hk = *(const float2*)&h_s[(kc + u) * 2]; \
        BFUP(B[u].x, we0, wo0) BFUP(B[u].y, we1, wo1) \
        BFUP(B[u].z, we2, wo2) BFUP(B[u].w, we3, wo3) \
        kav0.x += hk.x * we0 + hk.y * wo0; \
        kav0.y += hk.x * we1 + hk.y * wo1; \
        kav0.z += hk.x * we2 + hk.y * wo2; \
        kav0.w += hk.x * we3 + hk.y * wo3; } }
      PIPE4(10, ofs4, P4_LOAD, P4_FMA)
      if (kh) pka4[j4] = kav0;
    } else if (tid >= 384 && t + 1 < TB) {
      for (int idx = tid - 384; idx < 200; idx += 128)
        ((float4*)Gbuf_s)[idx] =
            ((const float4*)(G + ((size_t)b * TB + t + 1) * G4H))[idx];
    }
    __syncthreads();
    if (tid < 81) {
      const float4 bbv = ((const float4*)bka_s)[tid];
      const float4 p0 = pka4[tid];
      float4 v0;
      v0.x = kav0.x + p0.x + bbv.x; v0.y = kav0.y + p0.y + bbv.y;
      v0.z = kav0.z + p0.z + bbv.z; v0.w = kav0.w + p0.w + bbv.w;
      *(float4*)&ka_s[4 * tid] = v0;
    }
    __syncthreads();

    // ---- P5: least-used select (wave 0) + key norms (lanes 64-67) ----
    if (tid < 64) {
      const int l = tid;
      unsigned u0v = __float_as_uint(wu_s[l]);
      unsigned u1v = __float_as_uint(wu_s[l + 64]);
      if (u0v == 0x80000000u) u0v = 0u;
      if (u1v == 0x80000000u) u1v = 0u;
      u0v = (u0v & 0x80000000u) ? ~u0v : (u0v | 0x80000000u);
      u1v = (u1v & 0x80000000u) ? ~u1v : (u1v | 0x80000000u);
      unsigned long long k0 = ((unsigned long long)u0v << 32) | (unsigned)l;
      unsigned long long k1 = ((unsigned long long)u1v << 32) | (unsigned)(l + 64);
#pragma unroll
      for (int rsel = 0; rsel < RR; ++rsel) {
        unsigned long long mn = (k0 < k1) ? k0 : k1;
#pragma unroll
        for (int off = 32; off; off >>= 1) {
          const unsigned long long o = __shfl_xor(mn, off);
          if (o < mn) mn = o;
        }
        const int idx = (int)(mn & 0xFFFFFFFFull);
        if (l == 0) lu_s[rsel] = idx;
        if (idx == l)      k0 = ~0ull;
        if (idx == l + 64) k1 = ~0ull;
      }
    } else if (tid < 68) {
      const int q = tid - 64;
      float s = 0.f;
#pragma unroll
      for (int d4 = 0; d4 < 10; ++d4) {
        const float4 v = *(const float4*)&ka_s[q * DD + 4 * d4];
        s += v.x * v.x + v.y * v.y + v.z * v.z + v.w * v.w;
      }
      kn2_s[q] = s;
    }
    __syncthreads();

    // ---- P7 (P6 fused): ww inline; M = M*wlu + ww^T @ add ; row-norm ----
    if (tid < NN) {
      const int n = tid;
      const int l0 = lu_s[0], l1 = lu_s[1], l2 = lu_s[2], l3 = lu_s[3];
      const float wlu = (n == l0 || n == l1 || n == l2 || n == l3) ? 1.f : 0.f;
      const float sg = ka_s[320];
      const float oms = (1.f - sg) * wlu;
      const float wwv0 = sg * wr_s[n]          + oms;
      const float wwv1 = sg * wr_s[NN + n]     + oms;
      const float wwv2 = sg * wr_s[2 * NN + n] + oms;
      const float wwv3 = sg * wr_s[3 * NN + n] + oms;
      ww_s[n]          = wwv0;
      ww_s[NN + n]     = wwv1;
      ww_s[2 * NN + n] = wwv2;
      ww_s[3 * NN + n] = wwv3;
      float* Mr = &M_s[n * MST];
      const float* Ad = &ka_s[160];
      float mn2 = 0.f;
#pragma unroll
      for (int d4 = 0; d4 < 10; ++d4) {
        float4 m = *(const float4*)&Mr[4 * d4];
        m.x *= wlu; m.y *= wlu; m.z *= wlu; m.w *= wlu;
        const float4 av0 = *(const float4*)&Ad[0 * DD + 4 * d4];
        const float4 av1 = *(const float4*)&Ad[1 * DD + 4 * d4];
        const float4 av2 = *(const float4*)&Ad[2 * DD + 4 * d4];
        const float4 av3 = *(const float4*)&Ad[3 * DD + 4 * d4];
        m.x += wwv0 * av0.x + wwv1 * av1.x + wwv2 * av2.x + wwv3 * av3.x;
        m.y += wwv0 * av0.y + wwv1 * av1.y + wwv2 * av2.y + wwv3 * av3.y;
        m.z += wwv0 * av0.z + wwv1 * av1.z + wwv2 * av2.z + wwv3 * av3.z;
        m.w += wwv0 * av0.w + wwv1 * av1.w + wwv2 * av2.w + wwv3 * av3.w;
        *(float4*)&Mr[4 * d4] = m;
        mn2 += m.x * m.x + m.y * m.y + m.z * m.z + m.w * m.w;
      }
      Mn2_s[n] = mn2;
    }
    __syncthreads();

    // ---- P8: K = cosine(key, M): 512 lanes = 4 keys x 128 rows ----
    {
      const int q = tid >> 7, n = tid & (NN - 1);
      const float* Mr = &M_s[n * MST];
      const float* Ky = &ka_s[q * DD];
      float s = 0.f;
#pragma unroll
      for (int d4 = 0; d4 < 10; ++d4) {
        const float4 mv = *(const float4*)&Mr[4 * d4];
        const float4 kv = *(const float4*)&Ky[4 * d4];
        s += kv.x * mv.x + kv.y * mv.y + kv.z * mv.z + kv.w * mv.w;
      }
      Kp[q * NN + n] = s / sqrtf(kn2_s[q] * Mn2_s[n] + 1e-6f);
    }
    __syncthreads();

    // ---- P9: softmax over N (4 rows, waves 0-3) ----
    {
      const int w = tid >> 6, l = tid & 63;
      if (w < 4) {
        float* Kr = Kp + w * NN;
        const float v0 = Kr[l], v1 = Kr[l + 64];
        float mx = fmaxf(v0, v1);
#pragma unroll
        for (int off = 32; off; off >>= 1) mx = fmaxf(mx, __shfl_xor(mx, off));
        const float e0 = expf(v0 - mx), e1 = expf(v1 - mx);
        float s = e0 + e1;
#pragma unroll
        for (int off = 32; off; off >>= 1) s += __shfl_xor(s, off);
        const float inv = 1.f / s;
        Kr[l] = e0 * inv; Kr[l + 64] = e1 * inv;
      }
    }
    __syncthreads();

    // ---- P10: r = wr_t @ M (320 lanes = 40 groups x 8-way n-split) ;
    //      P11: wu update (lanes 320+) ----
    if (tid < 320) {
      const int g = tid >> 3, ns = tid & 7;   // g = q*10 + d4
      const int q = g / 10, d4 = g - q * 10;
      const float* Kr = Kp + q * NN;
      const float* Mb = &M_s[4 * d4];
      float4 acc = make_float4(0.f, 0.f, 0.f, 0.f);
#pragma unroll
      for (int j = 0; j < 16; ++j) {
        const int n = ns + 8 * j;
        const float kw = Kr[n];
        const float4 mv = *(const float4*)&Mb[n * MST];
        acc.x += kw * mv.x; acc.y += kw * mv.y;
        acc.z += kw * mv.z; acc.w += kw * mv.w;
      }
#pragma unroll
      for (int off = 4; off; off >>= 1) {
        acc.x += __shfl_xor(acc.x, off);
        acc.y += __shfl_xor(acc.y, off);
        acc.z += __shfl_xor(acc.z, off);
        acc.w += __shfl_xor(acc.w, off);
      }
      if (ns == 0) *(float4*)&r_s[q * DD + 4 * d4] = acc;
    } else if (tid < 448) {
      const int n = tid - 320;
      if (n < NN) {
        float s = 0.95f * wu_s[n];
#pragma unroll
        for (int q = 0; q < RR; ++q)
          s += Kp[q * NN + n] + ww_s[q * NN + n];
        wu_s[n] = s;
      }
    }
    __syncthreads();

    // ---- P12: out (wave 0) ; wr <- wr_t (waves 4-7) ----
    if (tid < 64) {
      const size_t ob = ((size_t)b * TB + t) * NCLS;
#pragma unroll
      for (int j = 0; j < NCLS; ++j) {
        float p = 0.f;
        for (int k = tid; k < HH; k += 64)      p += h_s[k] * Who_s[j * HH + k];
        for (int m = tid; m < RR * DD; m += 64) p += r_s[m] * Wro_s[j * RR * DD + m];
#pragma unroll
        for (int off = 32; off; off >>= 1) p += __shfl_xor(p, off);
        if (tid == 0) out[ob + j] = p + bo_s[j];
      }
    } else if (tid >= 256) {
      for (int f = tid - 256; f < RR * NN; f += 256) wr_s[f] = Kp[f];
    }
    __syncthreads();
  }
}

// ---------------------------------------------------------------------------
extern "C" void kernel_launch(void* const* d_in, const int* in_sizes, int n_in,
                              void* d_out, int out_size, void* d_ws, size_t ws_size,
                              hipStream_t stream) {
  const float* x    = (const float*)d_in[0];
  const float* Wkey = (const float*)d_in[1];
  const float* bkey = (const float*)d_in[2];
  const float* Wadd = (const float*)d_in[3];
  const float* badd = (const float*)d_in[4];
  const float* Wsig = (const float*)d_in[5];
  const float* bsig = (const float*)d_in[6];
  const float* Who  = (const float*)d_in[7];
  const float* bho  = (const float*)d_in[8];
  const float* Wro  = (const float*)d_in[9];
  const float* bro  = (const float*)d_in[10];
  const float* Wrh  = (const float*)d_in[11];
  const float* brh  = (const float*)d_in[12];
  const float* Wih  = (const float*)d_in[13];
  const float* bih  = (const float*)d_in[14];
  const float* Whh  = (const float*)d_in[15];
  const float* bhh  = (const float*)d_in[16];

  float* ws = (float*)d_ws;
  float* G  = ws;                                    // 25600*800 floats
  unsigned short* WhhP = (unsigned short*)(G + (size_t)25600 * 800); // 160,000 us
  unsigned short* WrhP = WhhP + 160000;              // 32,000 us
  unsigned short* WkaP = WrhP + 32000;               // 64,800 us
  float* bka = G + (size_t)25600 * 800 + 128400;     // after 256,800 ushorts

  prep_kernel<<<(160000 + 255) / 256, 256, 0, stream>>>(
      Whh, Wrh, Wkey, Wadd, Wsig, bkey, badd, bsig, WhhP, WrhP, WkaP, bka);

  dim3 gA(G4H / GN, 25600 / GM);   // (10, 200)
  gemm_in2_kernel<<<gA, 256, 0, stream>>>(x, Wih, bih, bhh, G);

  mann_kernel<<<BB, 512, 0, stream>>>(G, WhhP, WrhP, WkaP, bka, brh,
                                      Who, bho, Wro, bro, (float*)d_out);
}

// Round 13
// 1971.694 us; speedup vs baseline: 1.7493x; 1.1080x over previous
//
// MANN/NTM forward — R22: producer/consumer wave split.
// R21 established: L2 regime = per-wave address-stream SHAPE (block count
// irrelevant). Algebra: h_upd = h+r@Wrh^T+brh feeds ONLY gates (carry is h_t),
// so gates_t = G_t + h_{t-1}@Whh^T + r_{t-1}@Wc^T + bc with Wc=Whh·Wrh,
// bc=Whh·brh (precomputed). Waves 4-7 stream h@Whh during P4..P12 of the
// PREVIOUS step (7 barrier-interval segments, reg accumulator, same int4
// stride-200 sweep shape as old P2), write gates_s at P12. P1/P1b deleted;
// PA = r@Wc (80 loads, 200 lanes) replaces them. Locals remapped to waves
// 0-3 (P8 256 lanes x 2 keys; P10 160 + wu 96). Kp/pka de-aliased from gates.
#include <hip/hip_runtime.h>
#include <math.h>

#define TB   100
#define BB   256
#define INF_ 784
#define HH   200
#define RR   4
#define NN   128
#define DD   40
#define NCLS 5
#define G4H  800   // 4*H
#define KAW  324   // 160 key + 160 add + 1 sigma + 3 pad
#define MST  44    // padded M row stride

typedef __attribute__((ext_vector_type(8))) short bf16x8;
typedef __attribute__((ext_vector_type(4))) float f32x4;

__device__ __forceinline__ float sigmoidf_(float x) { return 1.0f / (1.0f + expf(-x)); }

__device__ __forceinline__ void splitbf_(float v, unsigned short &hi, unsigned short &lo) {
  const unsigned b = __float_as_uint(v);
  hi = (unsigned short)(b >> 16);
  const float hf = __uint_as_float(b & 0xFFFF0000u);
  lo = (unsigned short)(__float_as_uint(v - hf) >> 16);
}

__device__ __forceinline__ unsigned short bf16rne_(float v) {
  const unsigned u = __float_as_uint(v);
  return (unsigned short)((u + 0x7FFFu + ((u >> 16) & 1u)) >> 16);
}

#define ADV(c, CC) { ++(c); if ((c) == (CC)) (c) = 0; }

// 4-slot rotating software pipeline (3 chunks of loads in flight ahead of FMA).
#define PIPE4(CC, OFS, LOADM, FMAM)                                     \
  {                                                                     \
    int chL = (OFS), chF = (OFS);                                       \
    LOADM(w0, chL); ADV(chL, CC); LOADM(w1, chL); ADV(chL, CC);         \
    LOADM(w2, chL); ADV(chL, CC);                                       \
    _Pragma("unroll 1")                                                 \
    for (int g = 0; g < ((CC) - 3) / 4; ++g) {                          \
      LOADM(w3, chL); ADV(chL, CC); FMAM(w0, chF); ADV(chF, CC);        \
      LOADM(w0, chL); ADV(chL, CC); FMAM(w1, chF); ADV(chF, CC);        \
      LOADM(w1, chL); ADV(chL, CC); FMAM(w2, chF); ADV(chF, CC);        \
      LOADM(w2, chL); ADV(chL, CC); FMAM(w3, chF); ADV(chF, CC);        \
    }                                                                   \
    {                                                                   \
      constexpr int REMX = (CC) - 3 - 4 * (((CC) - 3) / 4);             \
      if (REMX >= 1) { LOADM(w3, chL); ADV(chL, CC); }                  \
      FMAM(w0, chF); ADV(chF, CC);                                      \
      if (REMX >= 2) { LOADM(w0, chL); ADV(chL, CC); }                  \
      FMAM(w1, chF); ADV(chF, CC);                                      \
      if (REMX >= 3) { LOADM(w1, chL); ADV(chL, CC); }                  \
      FMAM(w2, chF); ADV(chF, CC);                                      \
      if (REMX >= 1) { FMAM(w3, chF); ADV(chF, CC); }                   \
      if (REMX >= 2) { FMAM(w0, chF); ADV(chF, CC); }                   \
      if (REMX >= 3) { FMAM(w1, chF); ADV(chF, CC); }                   \
    }                                                                   \
  }

// bf16-pair unpack: one u32 = (k-even in low16, k-odd in high16)
#define BFUP(V, WE, WO)                                                  \
  const float WE = __uint_as_float((unsigned)(V) << 16);                 \
  const float WO = __uint_as_float((unsigned)(V) & 0xFFFF0000u);

// ---------------------------------------------------------------------------
// Prep: bf16 k-pair-packed weights + Wc = Whh@Wrh fold + bc = Whh@brh.
// Packed layout: idx = (k>>1)*(2*J) + j*2 + (k&1)
// ---------------------------------------------------------------------------
__global__ __launch_bounds__(256) void prep_kernel(
    const float* __restrict__ Whh, const float* __restrict__ Wrh,
    const float* __restrict__ Wkey, const float* __restrict__ Wadd,
    const float* __restrict__ Wsig, const float* __restrict__ bkey,
    const float* __restrict__ badd, const float* __restrict__ bsig,
    const float* __restrict__ brh,
    unsigned short* __restrict__ WhhP, unsigned short* __restrict__ WkaP,
    unsigned short* __restrict__ WcP, float* __restrict__ bka,
    float* __restrict__ bc)
{
  const int tid = blockIdx.x * 256 + threadIdx.x;
  if (tid < 160000) {            // Whh (800j, 200k) -> packed [k2][800][2]
    const int j = tid / 200, k = tid - j * 200;
    WhhP[(k >> 1) * 1600 + j * 2 + (k & 1)] = bf16rne_(Whh[tid]);
  }
  if (tid < 200 * KAW) {         // [Wkey|Wadd|Wsig] -> packed [k2][324][2]
    const int k = tid / KAW, j = tid - k * KAW;
    float v = 0.0f;
    if (j < 160)       v = Wkey[j * HH + k];
    else if (j < 320)  v = Wadd[(j - 160) * HH + k];
    else if (j == 320) v = Wsig[k];
    WkaP[(k >> 1) * (2 * KAW) + j * 2 + (k & 1)] = bf16rne_(v);
  }
  if (tid < 128000) {            // Wc[j][k] = sum_m Whh[j][m]*Wrh[m][k]
    const int j = tid / 160, k = tid - j * 160;
    const float* wrow = Whh + (size_t)j * 200;
    float s = 0.f;
#pragma unroll 4
    for (int m = 0; m < 200; ++m) s += wrow[m] * Wrh[(size_t)m * 160 + k];
    WcP[(k >> 1) * 1600 + j * 2 + (k & 1)] = bf16rne_(s);
  }
  if (tid < 800) {               // bc[j] = sum_m Whh[j][m]*brh[m]  (fp32)
    const float* wrow = Whh + (size_t)tid * 200;
    float s = 0.f;
#pragma unroll 4
    for (int m = 0; m < 200; ++m) s += wrow[m] * brh[m];
    bc[tid] = s;
  }
  if (tid < KAW) {
    float v = 0.0f;
    if (tid < 160)       v = bkey[tid];
    else if (tid < 320)  v = badd[tid - 160];
    else if (tid == 320) v = bsig[0];
    bka[tid] = v;
  }
}

// ---------------------------------------------------------------------------
// gemm_in2: G[m,j] = sum_k x[m,k]*Wih[j,k] + bih[j] + bhh[j]  (MFMA bf16,
// split-precision hi/lo). Tile 128(M) x 80(N), 256 thr = 4 waves, K-step 32.
// ---------------------------------------------------------------------------
#define GM  128
#define GN  80
#define LDK 40   // padded K stride in bf16 elems (80B, 16B-aligned rows)

__global__ __launch_bounds__(256) void gemm_in2_kernel(
    const float* __restrict__ X, const float* __restrict__ Wih,
    const float* __restrict__ bih, const float* __restrict__ bhh,
    float* __restrict__ G)
{
  __shared__ __attribute__((aligned(16))) unsigned short Ahi[GM][LDK];
  __shared__ __attribute__((aligned(16))) unsigned short Alo[GM][LDK];
  __shared__ __attribute__((aligned(16))) unsigned short Bhi[GN][LDK];
  __shared__ __attribute__((aligned(16))) unsigned short Blo[GN][LDK];

  const int tid  = threadIdx.x;
  const int wv   = tid >> 6, lane = tid & 63;
  const int n0   = blockIdx.x * GN;
  const int m0   = blockIdx.y * GM;

  f32x4 acc[2][5];
#pragma unroll
  for (int mt = 0; mt < 2; ++mt)
#pragma unroll
    for (int nt = 0; nt < 5; ++nt) acc[mt][nt] = (f32x4){0.f, 0.f, 0.f, 0.f};

  const int arow = tid >> 1, ak = (tid & 1) * 16;
  const float* Ap = X + (size_t)(m0 + arow) * INF_ + ak;
  const float* Bp = Wih + (size_t)(n0 + arow) * INF_ + ak;  // arow<80 when tid<160

  const int fr = lane & 15, fk = (lane >> 4) * 8;

  for (int kk = 0; kk < 800; kk += 32) {
    float va[16], vb[16];
    const bool av = (kk + ak) < INF_;
#pragma unroll
    for (int i = 0; i < 16; ++i) va[i] = 0.f;
    if (av) {
      *(float4*)&va[0]  = *(const float4*)(Ap + kk);
      *(float4*)&va[4]  = *(const float4*)(Ap + kk + 4);
      *(float4*)&va[8]  = *(const float4*)(Ap + kk + 8);
      *(float4*)&va[12] = *(const float4*)(Ap + kk + 12);
    }
    if (tid < 160) {
#pragma unroll
      for (int i = 0; i < 16; ++i) vb[i] = 0.f;
      if (av) {
        *(float4*)&vb[0]  = *(const float4*)(Bp + kk);
        *(float4*)&vb[4]  = *(const float4*)(Bp + kk + 4);
        *(float4*)&vb[8]  = *(const float4*)(Bp + kk + 8);
        *(float4*)&vb[12] = *(const float4*)(Bp + kk + 12);
      }
    }
    __syncthreads();   // prior compute done before LDS overwrite
    {
      unsigned ah[8], al[8];
#pragma unroll
      for (int i = 0; i < 8; ++i) {
        unsigned short h0, l0, h1, l1;
        splitbf_(va[2 * i], h0, l0);
        splitbf_(va[2 * i + 1], h1, l1);
        ah[i] = (unsigned)h0 | ((unsigned)h1 << 16);
        al[i] = (unsigned)l0 | ((unsigned)l1 << 16);
      }
      ((int4*)&Ahi[arow][ak])[0] = make_int4(ah[0], ah[1], ah[2], ah[3]);
      ((int4*)&Ahi[arow][ak + 8])[0] = make_int4(ah[4], ah[5], ah[6], ah[7]);
      ((int4*)&Alo[arow][ak])[0] = make_int4(al[0], al[1], al[2], al[3]);
      ((int4*)&Alo[arow][ak + 8])[0] = make_int4(al[4], al[5], al[6], al[7]);
    }
    if (tid < 160) {
      unsigned bh[8], bl[8];
#pragma unroll
      for (int i = 0; i < 8; ++i) {
        unsigned short h0, l0, h1, l1;
        splitbf_(vb[2 * i], h0, l0);
        splitbf_(vb[2 * i + 1], h1, l1);
        bh[i] = (unsigned)h0 | ((unsigned)h1 << 16);
        bl[i] = (unsigned)l0 | ((unsigned)l1 << 16);
      }
      ((int4*)&Bhi[arow][ak])[0] = make_int4(bh[0], bh[1], bh[2], bh[3]);
      ((int4*)&Bhi[arow][ak + 8])[0] = make_int4(bh[4], bh[5], bh[6], bh[7]);
      ((int4*)&Blo[arow][ak])[0] = make_int4(bl[0], bl[1], bl[2], bl[3]);
      ((int4*)&Blo[arow][ak + 8])[0] = make_int4(bl[4], bl[5], bl[6], bl[7]);
    }
    __syncthreads();
    const bf16x8 a0h = *(const bf16x8*)&Ahi[wv * 32 + fr][fk];
    const bf16x8 a0l = *(const bf16x8*)&Alo[wv * 32 + fr][fk];
    const bf16x8 a1h = *(const bf16x8*)&Ahi[wv * 32 + 16 + fr][fk];
    const bf16x8 a1l = *(const bf16x8*)&Alo[wv * 32 + 16 + fr][fk];
#pragma unroll
    for (int nt = 0; nt < 5; ++nt) {
      const bf16x8 bh = *(const bf16x8*)&Bhi[nt * 16 + fr][fk];
      const bf16x8 bl = *(const bf16x8*)&Blo[nt * 16 + fr][fk];
      acc[0][nt] = __builtin_amdgcn_mfma_f32_16x16x32_bf16(a0h, bh, acc[0][nt], 0, 0, 0);
      acc[1][nt] = __builtin_amdgcn_mfma_f32_16x16x32_bf16(a1h, bh, acc[1][nt], 0, 0, 0);
      acc[0][nt] = __builtin_amdgcn_mfma_f32_16x16x32_bf16(a0l, bh, acc[0][nt], 0, 0, 0);
      acc[1][nt] = __builtin_amdgcn_mfma_f32_16x16x32_bf16(a1l, bh, acc[1][nt], 0, 0, 0);
      acc[0][nt] = __builtin_amdgcn_mfma_f32_16x16x32_bf16(a0h, bl, acc[0][nt], 0, 0, 0);
      acc[1][nt] = __builtin_amdgcn_mfma_f32_16x16x32_bf16(a1h, bl, acc[1][nt], 0, 0, 0);
    }
  }

#pragma unroll
  for (int nt = 0; nt < 5; ++nt) {
    const int en = n0 + nt * 16 + fr;
    const float bs = bih[en] + bhh[en];
#pragma unroll
    for (int mt = 0; mt < 2; ++mt) {
      const int emb = m0 + wv * 32 + mt * 16 + (lane >> 4) * 4;
#pragma unroll
      for (int r = 0; r < 4; ++r)
        G[(size_t)(emb + r) * G4H + en] = acc[mt][nt][r] + bs;
    }
  }
}

// ---------------------------------------------------------------------------
// Recurrence: 256 blocks x 512 thr, 1 batch element each.
// Waves 0-3: local phases. Waves 4-7 (lanes 256-455): stream next step's
// h@Whh gates bulk across 7 barrier-interval segments.
// ---------------------------------------------------------------------------
__global__ __launch_bounds__(512, 2) void mann_kernel(
    const float* __restrict__ G, const unsigned short* __restrict__ WhhP,
    const unsigned short* __restrict__ WkaP, const unsigned short* __restrict__ WcP,
    const float* __restrict__ bka, const float* __restrict__ bc,
    const float* __restrict__ Who, const float* __restrict__ bho,
    const float* __restrict__ Wro, const float* __restrict__ bro,
    float* __restrict__ out)
{
  __shared__ __attribute__((aligned(16))) float M_s[NN * MST];
  __shared__ __attribute__((aligned(16))) float h_s[HH];
  __shared__ __attribute__((aligned(16))) float c_s[HH];
  __shared__ __attribute__((aligned(16))) float r_s[RR * DD];
  __shared__ float wr_s[RR * NN];
  __shared__ float ww_s[RR * NN];
  __shared__ float wu_s[NN];
  __shared__ float Mn2_s[NN];
  __shared__ float kn2_s[RR];
  __shared__ __attribute__((aligned(16))) float gates_s[G4H];
  __shared__ __attribute__((aligned(16))) float Kp_s[RR * NN];
  __shared__ __attribute__((aligned(16))) float ka_s[KAW];
  __shared__ __attribute__((aligned(16))) float bka_s[KAW];
  __shared__ __attribute__((aligned(16))) float bc_s[G4H];
  __shared__ __attribute__((aligned(16))) float pka_s[81 * 4];
  __shared__ float Who_s[NCLS * HH], Wro_s[NCLS * RR * DD], bo_s[NCLS];
  __shared__ int   lu_s[RR];

  const int tid = threadIdx.x;
  const int b   = blockIdx.x;
  const int jl  = tid - 256;           // ovl lane id (0..199 active)

  // ---- init ----
  for (int e = tid; e < NN * MST; e += 512) M_s[e] = 0.f;
  if (tid < RR * NN) { wr_s[tid] = 0.f; }
  if (tid < NN) wu_s[tid] = 0.f;
  if (tid < HH) { h_s[tid] = 0.f; c_s[tid] = 0.f; }
  if (tid < RR * DD) r_s[tid] = 0.f;
  if (tid < KAW) bka_s[tid] = bka[tid];
  for (int e = tid; e < NCLS * HH; e += 512) Who_s[e] = Who[e];
  for (int e = tid; e < NCLS * RR * DD; e += 512) Wro_s[e] = Wro[e];
  if (tid < NCLS) bo_s[tid] = bho[tid] + bro[tid];
  if (tid < 200) {
    ((float4*)bc_s)[tid] = ((const float4*)bc)[tid];
    // gates for t=0: G(0) + bc (h=r=0)
    const float4 gv = ((const float4*)(G + (size_t)b * TB * G4H))[tid];
    const float4 bcv = ((const float4*)bc)[tid];
    *(float4*)&gates_s[4 * tid] =
        make_float4(gv.x + bcv.x, gv.y + bcv.y, gv.z + bcv.z, gv.w + bcv.w);
  }
  __syncthreads();

  const int ofsc = (int)((blockIdx.x * 5u) % 16u);  // PA: 16 chunks
  const int ofs2 = (int)((blockIdx.x * 7u) % 20u);  // ovl: 20 chunks
  const int ofs4 = (int)((blockIdx.x * 3u) % 10u);  // P4: 10 chunks

  const int4* __restrict__ Wh4o = (const int4*)WhhP + ((jl >= 0 && jl < 200) ? jl : 0);

// ovl segment body: NCH chunks of {5 int4 loads, unpack+FMA}
#define OVL_SEG(NCH)                                                  \
  else if (jl >= 0 && jl < 200) {                                     \
    _Pragma("unroll")                                                 \
    for (int s = 0; s < (NCH); ++s) {                                 \
      int c2 = ochF + ofs2; if (c2 >= 20) c2 -= 20;                   \
      const int4* __restrict__ pp = Wh4o + (size_t)(c2 * 5) * 200;    \
      int4 vv[5];                                                     \
      _Pragma("unroll")                                               \
      for (int u = 0; u < 5; ++u) vv[u] = pp[u * 200];                \
      const int kc0 = c2 * 5;                                         \
      _Pragma("unroll")                                               \
      for (int u = 0; u < 5; ++u) {                                   \
        const float2 hk = *(const float2*)&h_s[(kc0 + u) * 2];        \
        BFUP(vv[u].x, we0, wo0) BFUP(vv[u].y, we1, wo1)               \
        BFUP(vv[u].z, we2, wo2) BFUP(vv[u].w, we3, wo3)               \
        oacc.x += hk.x * we0 + hk.y * wo0;                            \
        oacc.y += hk.x * we1 + hk.y * wo1;                            \
        oacc.z += hk.x * we2 + hk.y * wo2;                            \
        oacc.w += hk.x * we3 + hk.y * wo3;                            \
      }                                                               \
      ++ochF;                                                         \
    }                                                                 \
  }

#pragma clang loop unroll(disable)
  for (int t = 0; t < TB; ++t) {
    float4 oacc = make_float4(0.f, 0.f, 0.f, 0.f);
    int ochF = 0;
    float4 g0 = make_float4(0.f, 0.f, 0.f, 0.f);

    // ---- PA: gates += r_{t-1} @ Wc^T (200 lanes, 80 k-pairs, 16 chunks) ----
    if (tid < 200) {
      const int4* __restrict__ Wc4 = (const int4*)WcP + tid;
      g0 = *(const float4*)&gates_s[4 * tid];
      int4 w0[5], w1[5], w2[5], w3[5];
#define PA_LOAD(B, CH) { const int kk = (CH) * 5; _Pragma("unroll") \
      for (int u = 0; u < 5; ++u) B[u] = Wc4[(kk + u) * 200]; }
#define PA_FMA(B, CH) { const int kc = (CH) * 5; _Pragma("unroll") \
      for (int u = 0; u < 5; ++u) { \
        const float2 rk = *(const float2*)&r_s[(kc + u) * 2]; \
        BFUP(B[u].x, we0, wo0) BFUP(B[u].y, we1, wo1) \
        BFUP(B[u].z, we2, wo2) BFUP(B[u].w, we3, wo3) \
        g0.x += rk.x * we0 + rk.y * wo0; \
        g0.y += rk.x * we1 + rk.y * wo1; \
        g0.z += rk.x * we2 + rk.y * wo2; \
        g0.w += rk.x * we3 + rk.y * wo3; } }
      PIPE4(16, ofsc, PA_LOAD, PA_FMA)
      *(float4*)&gates_s[4 * tid] = g0;
    }
    __syncthreads();   // B0

    // ---- P3: LSTM pointwise (200 lanes) -> h_t ----
    if (tid < HH) {
      const float ig = sigmoidf_(gates_s[tid]);
      const float fg = sigmoidf_(gates_s[HH + tid]);
      const float gg = tanhf(gates_s[2 * HH + tid]);
      const float og = sigmoidf_(gates_s[3 * HH + tid]);
      const float cn = fg * c_s[tid] + ig * gg;
      c_s[tid] = cn;
      h_s[tid] = og * tanhf(cn);
    }
    __syncthreads();   // B1

    // ---- P4a: ka partials (162 lanes) ; ovl seg1: init + 3 chunks ----
    float4 kav0 = make_float4(0.f, 0.f, 0.f, 0.f);
    if (tid < 162) {
      const int kh = tid / 81, j4 = tid - kh * 81;
      const int k2beg = kh * 50;
      const int4* __restrict__ Wk4 = (const int4*)WkaP + (size_t)k2beg * 81 + j4;
      int4 w0[5], w1[5], w2[5], w3[5];
#define P4_LOAD(B, CH) { const int kk = (CH) * 5; _Pragma("unroll") \
      for (int u = 0; u < 5; ++u) B[u] = Wk4[(kk + u) * 81]; }
#define P4_FMA(B, CH) { const int kc = k2beg + (CH) * 5; _Pragma("unroll") \
      for (int u = 0; u < 5; ++u) { \
        const float2 hk = *(const float2*)&h_s[(kc + u) * 2]; \
        BFUP(B[u].x, we0, wo0) BFUP(B[u].y, we1, wo1) \
        BFUP(B[u].z, we2, wo2) BFUP(B[u].w, we3, wo3) \
        kav0.x += hk.x * we0 + hk.y * wo0; \
        kav0.y += hk.x * we1 + hk.y * wo1; \
        kav0.z += hk.x * we2 + hk.y * wo2; \
        kav0.w += hk.x * we3 + hk.y * wo3; } }
      PIPE4(10, ofs4, P4_LOAD, P4_FMA)
      if (kh) ((float4*)pka_s)[j4] = kav0;
    }
    else if (jl >= 0 && jl < 200) {
      const int tn = (t + 1 < TB) ? t + 1 : t;
      const float4 gv = *((const float4*)(G + ((size_t)b * TB + tn) * G4H) + jl);
      const float4 bcv = ((const float4*)bc_s)[jl];
      oacc = make_float4(gv.x + bcv.x, gv.y + bcv.y, gv.z + bcv.z, gv.w + bcv.w);
      _Pragma("unroll")
      for (int s = 0; s < 3; ++s) {
        int c2 = ochF + ofs2; if (c2 >= 20) c2 -= 20;
        const int4* __restrict__ pp = Wh4o + (size_t)(c2 * 5) * 200;
        int4 vv[5];
        _Pragma("unroll")
        for (int u = 0; u < 5; ++u) vv[u] = pp[u * 200];
        const int kc0 = c2 * 5;
        _Pragma("unroll")
        for (int u = 0; u < 5; ++u) {
          const float2 hk = *(const float2*)&h_s[(kc0 + u) * 2];
          BFUP(vv[u].x, we0, wo0) BFUP(vv[u].y, we1, wo1)
          BFUP(vv[u].z, we2, wo2) BFUP(vv[u].w, we3, wo3)
          oacc.x += hk.x * we0 + hk.y * wo0;
          oacc.y += hk.x * we1 + hk.y * wo1;
          oacc.z += hk.x * we2 + hk.y * wo2;
          oacc.w += hk.x * we3 + hk.y * wo3;
        }
        ++ochF;
      }
    }
    __syncthreads();   // B2

    // ---- P4b: finalize ka (81 lanes) ; ovl seg2 ----
    if (tid < 81) {
      const float4 bbv = ((const float4*)bka_s)[tid];
      const float4 p0 = ((const float4*)pka_s)[tid];
      float4 v0;
      v0.x = kav0.x + p0.x + bbv.x; v0.y = kav0.y + p0.y + bbv.y;
      v0.z = kav0.z + p0.z + bbv.z; v0.w = kav0.w + p0.w + bbv.w;
      *(float4*)&ka_s[4 * tid] = v0;
    }
    OVL_SEG(3)
    __syncthreads();   // B3

    // ---- P5: least-used select (wave 0) + key norms (lanes 64-67) ; seg3 ----
    if (tid < 64) {
      const int l = tid;
      unsigned u0v = __float_as_uint(wu_s[l]);
      unsigned u1v = __float_as_uint(wu_s[l + 64]);
      if (u0v == 0x80000000u) u0v = 0u;
      if (u1v == 0x80000000u) u1v = 0u;
      u0v = (u0v & 0x80000000u) ? ~u0v : (u0v | 0x80000000u);
      u1v = (u1v & 0x80000000u) ? ~u1v : (u1v | 0x80000000u);
      unsigned long long k0 = ((unsigned long long)u0v << 32) | (unsigned)l;
      unsigned long long k1 = ((unsigned long long)u1v << 32) | (unsigned)(l + 64);
#pragma unroll
      for (int rsel = 0; rsel < RR; ++rsel) {
        unsigned long long mn = (k0 < k1) ? k0 : k1;
#pragma unroll
        for (int off = 32; off; off >>= 1) {
          const unsigned long long o = __shfl_xor(mn, off);
          if (o < mn) mn = o;
        }
        const int idx = (int)(mn & 0xFFFFFFFFull);
        if (l == 0) lu_s[rsel] = idx;
        if (idx == l)      k0 = ~0ull;
        if (idx == l + 64) k1 = ~0ull;
      }
    } else if (tid < 68) {
      const int q = tid - 64;
      float s = 0.f;
#pragma unroll
      for (int d4 = 0; d4 < 10; ++d4) {
        const float4 v = *(const float4*)&ka_s[q * DD + 4 * d4];
        s += v.x * v.x + v.y * v.y + v.z * v.z + v.w * v.w;
      }
      kn2_s[q] = s;
    }
    OVL_SEG(3)
    __syncthreads();   // B4

    // ---- P7 (P6 fused): ww inline; M update + row-norm (128 lanes) ; seg4 ----
    if (tid < NN) {
      const int n = tid;
      const int l0 = lu_s[0], l1 = lu_s[1], l2 = lu_s[2], l3 = lu_s[3];
      const float wlu = (n == l0 || n == l1 || n == l2 || n == l3) ? 1.f : 0.f;
      const float sg = ka_s[320];
      const float oms = (1.f - sg) * wlu;
      const float wwv0 = sg * wr_s[n]          + oms;
      const float wwv1 = sg * wr_s[NN + n]     + oms;
      const float wwv2 = sg * wr_s[2 * NN + n] + oms;
      const float wwv3 = sg * wr_s[3 * NN + n] + oms;
      ww_s[n]          = wwv0;
      ww_s[NN + n]     = wwv1;
      ww_s[2 * NN + n] = wwv2;
      ww_s[3 * NN + n] = wwv3;
      float* Mr = &M_s[n * MST];
      const float* Ad = &ka_s[160];
      float mn2 = 0.f;
#pragma unroll
      for (int d4 = 0; d4 < 10; ++d4) {
        float4 m = *(const float4*)&Mr[4 * d4];
        m.x *= wlu; m.y *= wlu; m.z *= wlu; m.w *= wlu;
        const float4 av0 = *(const float4*)&Ad[0 * DD + 4 * d4];
        const float4 av1 = *(const float4*)&Ad[1 * DD + 4 * d4];
        const float4 av2 = *(const float4*)&Ad[2 * DD + 4 * d4];
        const float4 av3 = *(const float4*)&Ad[3 * DD + 4 * d4];
        m.x += wwv0 * av0.x + wwv1 * av1.x + wwv2 * av2.x + wwv3 * av3.x;
        m.y += wwv0 * av0.y + wwv1 * av1.y + wwv2 * av2.y + wwv3 * av3.y;
        m.z += wwv0 * av0.z + wwv1 * av1.z + wwv2 * av2.z + wwv3 * av3.z;
        m.w += wwv0 * av0.w + wwv1 * av1.w + wwv2 * av2.w + wwv3 * av3.w;
        *(float4*)&Mr[4 * d4] = m;
        mn2 += m.x * m.x + m.y * m.y + m.z * m.z + m.w * m.w;
      }
      Mn2_s[n] = mn2;
    }
    OVL_SEG(3)
    __syncthreads();   // B5

    // ---- P8: K = cosine(key, M): 256 lanes x 2 keys ; seg5 ----
    if (tid < 256) {
      const int qq = tid >> 7, n = tid & (NN - 1);
      const float* Mr = &M_s[n * MST];
      const float* Ky0 = &ka_s[qq * DD];
      const float* Ky1 = &ka_s[(qq + 2) * DD];
      float s0 = 0.f, s1 = 0.f;
#pragma unroll
      for (int d4 = 0; d4 < 10; ++d4) {
        const float4 mv = *(const float4*)&Mr[4 * d4];
        const float4 k0v = *(const float4*)&Ky0[4 * d4];
        const float4 k1v = *(const float4*)&Ky1[4 * d4];
        s0 += k0v.x * mv.x + k0v.y * mv.y + k0v.z * mv.z + k0v.w * mv.w;
        s1 += k1v.x * mv.x + k1v.y * mv.y + k1v.z * mv.z + k1v.w * mv.w;
      }
      const float mn2 = Mn2_s[n];
      Kp_s[qq * NN + n]       = s0 / sqrtf(kn2_s[qq] * mn2 + 1e-6f);
      Kp_s[(qq + 2) * NN + n] = s1 / sqrtf(kn2_s[qq + 2] * mn2 + 1e-6f);
    }
    OVL_SEG(3)
    __syncthreads();   // B6

    // ---- P9: softmax over N (4 rows, waves 0-3) ; seg6 ----
    if (tid < 256) {
      const int w = tid >> 6, l = tid & 63;
      float* Kr = Kp_s + w * NN;
      const float v0 = Kr[l], v1 = Kr[l + 64];
      float mx = fmaxf(v0, v1);
#pragma unroll
      for (int off = 32; off; off >>= 1) mx = fmaxf(mx, __shfl_xor(mx, off));
      const float e0 = expf(v0 - mx), e1 = expf(v1 - mx);
      float s = e0 + e1;
#pragma unroll
      for (int off = 32; off; off >>= 1) s += __shfl_xor(s, off);
      const float inv = 1.f / s;
      Kr[l] = e0 * inv; Kr[l + 64] = e1 * inv;
    }
    OVL_SEG(3)
    __syncthreads();   // B7

    // ---- P10: r = wr_t @ M (160 lanes, 4-way n-split) ; P11: wu (96) ; seg7 ----
    if (tid < 160) {
      const int g = tid >> 2, ns = tid & 3;   // g = q*10 + d4
      const int q = g / 10, d4 = g - q * 10;
      const float* Kr = Kp_s + q * NN;
      const float* Mb = &M_s[4 * d4];
      float4 acc = make_float4(0.f, 0.f, 0.f, 0.f);
#pragma unroll
      for (int j = 0; j < 32; ++j) {
        const int n = ns + 4 * j;
        const float kw = Kr[n];
        const float4 mv = *(const float4*)&Mb[n * MST];
        acc.x += kw * mv.x; acc.y += kw * mv.y;
        acc.z += kw * mv.z; acc.w += kw * mv.w;
      }
#pragma unroll
      for (int off = 2; off; off >>= 1) {
        acc.x += __shfl_xor(acc.x, off);
        acc.y += __shfl_xor(acc.y, off);
        acc.z += __shfl_xor(acc.z, off);
        acc.w += __shfl_xor(acc.w, off);
      }
      if (ns == 0) *(float4*)&r_s[q * DD + 4 * d4] = acc;
    } else if (tid < 256) {
      for (int n = tid - 160; n < NN; n += 96) {
        float s = 0.95f * wu_s[n];
#pragma unroll
        for (int q = 0; q < RR; ++q)
          s += Kp_s[q * NN + n] + ww_s[q * NN + n];
        wu_s[n] = s;
      }
    }
    OVL_SEG(2)
    __syncthreads();   // B8

    // ---- P12: out (wave 0) ; wr <- Kp (waves 1-3) ; ovl writeout ----
    if (tid < 64) {
      const size_t ob = ((size_t)b * TB + t) * NCLS;
#pragma unroll
      for (int j = 0; j < NCLS; ++j) {
        float p = 0.f;
        for (int k = tid; k < HH; k += 64)      p += h_s[k] * Who_s[j * HH + k];
        for (int m = tid; m < RR * DD; m += 64) p += r_s[m] * Wro_s[j * RR * DD + m];
#pragma unroll
        for (int off = 32; off; off >>= 1) p += __shfl_xor(p, off);
        if (tid == 0) out[ob + j] = p + bo_s[j];
      }
    } else if (tid < 256) {
      for (int f = tid - 64; f < RR * NN; f += 192) wr_s[f] = Kp_s[f];
    } else if (jl < 200) {
      *(float4*)&gates_s[4 * jl] = oacc;
    }
    __syncthreads();   // B9
  }
}

// ---------------------------------------------------------------------------
extern "C" void kernel_launch(void* const* d_in, const int* in_sizes, int n_in,
                              void* d_out, int out_size, void* d_ws, size_t ws_size,
                              hipStream_t stream) {
  const float* x    = (const float*)d_in[0];
  const float* Wkey = (const float*)d_in[1];
  const float* bkey = (const float*)d_in[2];
  const float* Wadd = (const float*)d_in[3];
  const float* badd = (const float*)d_in[4];
  const float* Wsig = (const float*)d_in[5];
  const float* bsig = (const float*)d_in[6];
  const float* Who  = (const float*)d_in[7];
  const float* bho  = (const float*)d_in[8];
  const float* Wro  = (const float*)d_in[9];
  const float* bro  = (const float*)d_in[10];
  const float* Wrh  = (const float*)d_in[11];
  const float* brh  = (const float*)d_in[12];
  const float* Wih  = (const float*)d_in[13];
  const float* bih  = (const float*)d_in[14];
  const float* Whh  = (const float*)d_in[15];
  const float* bhh  = (const float*)d_in[16];

  float* ws = (float*)d_ws;
  float* G  = ws;                                        // 25600*800 floats
  unsigned short* WhhP = (unsigned short*)(G + (size_t)25600 * 800); // 160,000
  unsigned short* WkaP = WhhP + 160000;                  // 64,800
  unsigned short* WcP  = WkaP + 64800;                   // 128,000 (tot 352,800 us = 176,400 fl)
  float* bka = G + (size_t)25600 * 800 + 176400;         // 324
  float* bc  = bka + 324;                                // 800

  prep_kernel<<<(160000 + 255) / 256, 256, 0, stream>>>(
      Whh, Wrh, Wkey, Wadd, Wsig, bkey, badd, bsig, brh,
      WhhP, WkaP, WcP, bka, bc);

  dim3 gA(G4H / GN, 25600 / GM);   // (10, 200)
  gemm_in2_kernel<<<gA, 256, 0, stream>>>(x, Wih, bih, bhh, G);

  mann_kernel<<<BB, 512, 0, stream>>>(G, WhhP, WkaP, WcP, bka, bc,
                                      Who, bho, Wro, bro, (float*)d_out);
}